// Round 5
// baseline (1096.716 us; speedup 1.0000x reference)
//
#include <hip/hip_runtime.h>

typedef unsigned short u16;
typedef unsigned int u32;
typedef __attribute__((ext_vector_type(4))) float f32x4;
typedef __attribute__((ext_vector_type(8))) __bf16 bf16x8;
typedef __attribute__((ext_vector_type(2))) __bf16 bf16x2;
typedef __attribute__((ext_vector_type(4))) u16 u16x4;

#define NB 2
#define NS 2048
#define ND 1024
#define NH 16
#define NHD 64
#define NFF 4096
#define NBS (NB * NS)   // 4096 rows

typedef const __attribute__((address_space(1))) unsigned int as1_u32;
typedef __attribute__((address_space(3))) unsigned int as3_u32;

__device__ __forceinline__ void gl_lds16(const u16* g, u16* l) {
  __builtin_amdgcn_global_load_lds((as1_u32*)g, (as3_u32*)l, 16, 0, 0);
}

__device__ __forceinline__ u16 f2bf(float f) {
  union { float f; unsigned u; } v; v.f = f;
  unsigned r = (v.u + 0x7FFFu + ((v.u >> 16) & 1u)) >> 16;  // RNE
  return (u16)r;
}

__device__ __forceinline__ float bf2f(u16 u) {
  union { u32 u; float f; } v; v.u = ((u32)u) << 16; return v.f;
}

// packed f32x2 -> bf16x2 (compiler emits v_cvt_pk_bf16_f32)
__device__ __forceinline__ u32 pkbf(float a, float b) {
  bf16x2 v; v[0] = (__bf16)a; v[1] = (__bf16)b;
  union { bf16x2 v; u32 u; } c; c.v = v; return c.u;
}

// ---------------- f32 -> bf16 (vectorized) ----------------
__global__ __launch_bounds__(256) void conv_bf16(const float* __restrict__ in,
                                                 u16* __restrict__ out, int n4) {
  int i = blockIdx.x * 256 + threadIdx.x;
  if (i >= n4) return;
  f32x4 v = *reinterpret_cast<const f32x4*>(&in[(size_t)i * 4]);
  u16x4 o;
#pragma unroll
  for (int j = 0; j < 4; ++j) o[j] = f2bf(v[j]);
  *reinterpret_cast<u16x4*>(&out[(size_t)i * 4]) = o;
}

// ---------------- weight convert + transpose: [K,N] f32 -> [N,K] bf16 ----------------
__global__ void wconv_t(const float* __restrict__ in, u16* __restrict__ out, int K, int N) {
  __shared__ float t[32][33];
  int n0 = blockIdx.x * 32, k0 = blockIdx.y * 32;
  int tx = threadIdx.x, ty = threadIdx.y;  // 32 x 8
#pragma unroll
  for (int i = ty; i < 32; i += 8) t[i][tx] = in[(size_t)(k0 + i) * N + n0 + tx];
  __syncthreads();
#pragma unroll
  for (int i = ty; i < 32; i += 8)
    out[(size_t)(n0 + i) * K + k0 + tx] = f2bf(t[tx][i]);
}

// ---------------- GEMM, 2-phase double-buffered ----------------
template <int TM, int OUTF32, int RELU>
__global__ __launch_bounds__(256) void gemm_bt(const u16* __restrict__ A,
                                               const u16* __restrict__ BT,
                                               const float* __restrict__ bias,
                                               float* __restrict__ Cf,
                                               u16* __restrict__ Cb,
                                               int M, int N, int K) {
  constexpr int MR = TM / 32;
  constexpr int ACH = TM / 64;
  __shared__ __align__(16) u16 lA[2][TM * 32];
  __shared__ __align__(16) u16 lB[2][128 * 32];
  const int tid = threadIdx.x;
  const int lane = tid & 63, wave = tid >> 6;
  const int bm = blockIdx.y * TM, bn = blockIdx.x * 128;
  const int wr = (wave >> 1) * (MR * 16), wc = (wave & 1) * 64;
  const int r16 = lane & 15, kg = lane >> 4;

  f32x4 acc[MR][4] = {};

  auto stage = [&](int buf, int k0) {
#pragma unroll
    for (int c = 0; c < ACH; ++c) {
      int chunk = c * 256 + tid;
      int r = chunk >> 2, kc = (chunk & 3) * 8;
      gl_lds16(&A[(size_t)(bm + r) * K + k0 + kc], &lA[buf][(c * 256 + wave * 64) * 8]);
    }
#pragma unroll
    for (int c = 0; c < 2; ++c) {
      int chunk = c * 256 + tid;
      int r = chunk >> 2, kc = (chunk & 3) * 8;
      gl_lds16(&BT[(size_t)(bn + r) * K + k0 + kc], &lB[buf][(c * 256 + wave * 64) * 8]);
    }
  };

  stage(0, 0);
  __syncthreads();

  const int nk = K / 32;
  for (int i = 0; i < nk; ++i) {
    const int cur = i & 1;
    if (i + 1 < nk) stage(cur ^ 1, (i + 1) * 32);

    bf16x8 af[MR], bfr[4];
#pragma unroll
    for (int m = 0; m < MR; ++m)
      af[m] = *reinterpret_cast<const bf16x8*>(&lA[cur][(wr + m * 16 + r16) * 32 + kg * 8]);
#pragma unroll
    for (int n = 0; n < 4; ++n)
      bfr[n] = *reinterpret_cast<const bf16x8*>(&lB[cur][(wc + n * 16 + r16) * 32 + kg * 8]);
#pragma unroll
    for (int m = 0; m < MR; ++m)
#pragma unroll
      for (int n = 0; n < 4; ++n)
        acc[m][n] = __builtin_amdgcn_mfma_f32_16x16x32_bf16(af[m], bfr[n], acc[m][n], 0, 0, 0);

    __syncthreads();
  }

#pragma unroll
  for (int m = 0; m < MR; ++m) {
    int row = bm + wr + m * 16 + kg * 4;
#pragma unroll
    for (int n = 0; n < 4; ++n) {
      int col = bn + wc + n * 16 + r16;
      float bv = bias[col];
#pragma unroll
      for (int j = 0; j < 4; ++j) {
        float v = acc[m][n][j] + bv;
        if (RELU) v = fmaxf(v, 0.f);
        if (OUTF32)
          Cf[(size_t)(row + j) * N + col] = v;
        else
          Cb[(size_t)(row + j) * N + col] = f2bf(v);
      }
    }
  }
}

// ---------------- V transpose via LDS: 64x64 tiles ----------------
__global__ __launch_bounds__(256) void vt_kern(const u16* __restrict__ src, int stride,
                                               int hmul, int hadd, u16* __restrict__ VT) {
  __shared__ u16 lt[64][72];
  const int bh = blockIdx.y;
  const int b = bh >> 4, h = bh & 15;
  const int s0 = blockIdx.x * 64;
  const u16* sb = src + (size_t)b * NS * stride + h * hmul + hadd;
#pragma unroll
  for (int c = 0; c < 2; ++c) {
    int chunk = c * 256 + threadIdx.x;
    int r = chunk >> 3, d = (chunk & 7) * 8;
    *reinterpret_cast<uint4*>(&lt[r][d]) =
        *reinterpret_cast<const uint4*>(&sb[(size_t)(s0 + r) * stride + d]);
  }
  __syncthreads();
  const int d = threadIdx.x >> 2, sq = (threadIdx.x & 3) * 16;
  union { u16 e[16]; uint4 v[2]; } pk;
#pragma unroll
  for (int i = 0; i < 16; ++i) pk.e[i] = lt[sq + i][d];
  uint4* dst = reinterpret_cast<uint4*>(&VT[((size_t)bh * NHD + d) * NS + s0 + sq]);
  dst[0] = pk.v[0];
  dst[1] = pk.v[1];
}

// ---------------- flash attention v5: KV-split + lane-local softmax ----------------
// grid (512, 2): blockIdx.y = KV split. 4096 waves -> 16 waves/CU.
// Per-tile common path has ZERO cross-lane DS ops: max-reduce gated by __all
// (defer-max T13), l-reduce deferred to epilogue. Writes un-normalized bf16
// partials + (m,l); attn_comb merges.
#define LPP 72
#define C1F 0.180336880f  // 0.125 * log2(e)
#define OPSZ ((size_t)32 * NS * NHD)

template <int CAUSAL>
__global__ __launch_bounds__(256, 4) void attn5(const u16* __restrict__ Qp, int qstride,
                                                int qhm, const u16* __restrict__ Kp,
                                                int kstride, int khm, int kha,
                                                const u16* __restrict__ VT,
                                                u16* __restrict__ OP,
                                                float2* __restrict__ ML) {
  const int bid = blockIdx.x;              // 512
  const int split = blockIdx.y;            // 0/1
  const int xcd = bid & 7, j5 = bid >> 3;
  const int bh = xcd + 8 * (j5 >> 4);      // 4 bh per XCD
  int qt = j5 & 15;
  if (CAUSAL) qt = 15 - qt;                // heavy q-tiles first
  const int b = bh >> 4, h = bh & 15;
  const int tid = threadIdx.x, lane = tid & 63, wave = tid >> 6;
  const int r16 = lane & 15, kg = lane >> 4;
  const int q0w = qt * 128 + wave * 32;

  __shared__ __align__(16) u16 lP[4][32 * LPP];
  u16* lPw = &lP[wave][0];

  const u16* qb = Qp + (size_t)b * NS * qstride + h * qhm;
  const u16* kb = Kp + (size_t)b * NS * kstride + h * khm + kha;
  const u16* vb = VT + (size_t)bh * NHD * NS;

  bf16x8 qf[2][2];
#pragma unroll
  for (int qn = 0; qn < 2; ++qn)
#pragma unroll
    for (int ks = 0; ks < 2; ++ks)
      qf[qn][ks] = *reinterpret_cast<const bf16x8*>(
          &qb[(size_t)(q0w + qn * 16 + r16) * qstride + ks * 32 + kg * 8]);

  f32x4 o_acc[2][4] = {};
  float m_run[2] = {-1e30f, -1e30f}, l_lane[2] = {0.f, 0.f};
  bf16x8 kfA[8], kfB[8], vf[8];

  const int ntw = CAUSAL ? (q0w / 64 + 1) : (NS / 64);
  const int half = (ntw + 1) >> 1;
  const int t0 = split ? half : 0;
  const int t1 = split ? ntw : half;

  auto loadK = [&](auto& dst, int kv0) {
#pragma unroll
    for (int c = 0; c < 4; ++c)
#pragma unroll
      for (int ks = 0; ks < 2; ++ks)
        dst[c * 2 + ks] = *reinterpret_cast<const bf16x8*>(
            &kb[(size_t)(kv0 + c * 16 + r16) * kstride + ks * 32 + kg * 8]);
  };

  auto tile = [&](auto& kf, auto& kn, int t, bool pre) {
    const int kv0 = t * 64;
    // V issued first; consumed last (latency hides under QK + softmax)
#pragma unroll
    for (int cd = 0; cd < 4; ++cd)
#pragma unroll
      for (int ks = 0; ks < 2; ++ks)
        vf[cd * 2 + ks] = *reinterpret_cast<const bf16x8*>(
            &vb[(size_t)(cd * 16 + r16) * NS + kv0 + ks * 32 + kg * 8]);

    // S^T = K @ Q^T (raw scores)
    f32x4 s[2][4] = {};
#pragma unroll
    for (int c = 0; c < 4; ++c)
#pragma unroll
      for (int ks = 0; ks < 2; ++ks) {
        s[0][c] = __builtin_amdgcn_mfma_f32_16x16x32_bf16(kf[c * 2 + ks], qf[0][ks], s[0][c], 0, 0, 0);
        s[1][c] = __builtin_amdgcn_mfma_f32_16x16x32_bf16(kf[c * 2 + ks], qf[1][ks], s[1][c], 0, 0, 0);
      }

    if (pre) loadK(kn, kv0 + 64);

#pragma unroll
    for (int qn = 0; qn < 2; ++qn) {
      // mask only the diagonal tile (wave-uniform branch)
      if (CAUSAL && t == ntw - 1) {
        const int q = q0w + qn * 16 + r16;
#pragma unroll
        for (int c = 0; c < 4; ++c)
#pragma unroll
          for (int j = 0; j < 4; ++j)
            if (kv0 + c * 16 + kg * 4 + j > q) s[qn][c][j] = -1e31f;
      }
      // lane-local max (raw domain)
      float mxr = s[qn][0][0];
#pragma unroll
      for (int c = 0; c < 4; ++c)
#pragma unroll
        for (int j = 0; j < 4; ++j) mxr = fmaxf(mxr, s[qn][c][j]);
      float mn = m_run[qn];
      if (!__all(mxr * C1F <= mn + 8.f)) {   // rescale: rare
        float mz = mxr * C1F;
        mz = fmaxf(mz, __shfl_xor(mz, 16));
        mz = fmaxf(mz, __shfl_xor(mz, 32));
        mn = fmaxf(m_run[qn], mz);
        const float cr = exp2f(m_run[qn] - mn);
        m_run[qn] = mn;
        l_lane[qn] *= cr;
        float crow[4];
#pragma unroll
        for (int j = 0; j < 4; ++j) crow[j] = __shfl(cr, kg * 4 + j);
#pragma unroll
        for (int cd = 0; cd < 4; ++cd)
#pragma unroll
          for (int j = 0; j < 4; ++j) o_acc[qn][cd][j] *= crow[j];
      }
      // exp in exp2 domain; per-lane partial sum (no cross-lane op)
      float su = 0.f;
#pragma unroll
      for (int c = 0; c < 4; ++c)
#pragma unroll
        for (int j = 0; j < 4; ++j) {
          float p = exp2f(fmaf(s[qn][c][j], C1F, -mn));
          s[qn][c][j] = p;
          su += p;
        }
      l_lane[qn] += su;

      // P -> wave-private LDS (b64 packed writes)
#pragma unroll
      for (int c = 0; c < 4; ++c) {
        uint2 w2 = {pkbf(s[qn][c][0], s[qn][c][1]), pkbf(s[qn][c][2], s[qn][c][3])};
        *reinterpret_cast<uint2*>(&lPw[(qn * 16 + r16) * LPP + c * 16 + kg * 4]) = w2;
      }
    }

    // PV
    bf16x8 pf[2][2];
#pragma unroll
    for (int qn = 0; qn < 2; ++qn)
#pragma unroll
      for (int ks = 0; ks < 2; ++ks)
        pf[qn][ks] = *reinterpret_cast<const bf16x8*>(
            &lPw[(qn * 16 + r16) * LPP + ks * 32 + kg * 8]);
#pragma unroll
    for (int cd = 0; cd < 4; ++cd)
#pragma unroll
      for (int ks = 0; ks < 2; ++ks) {
        o_acc[0][cd] = __builtin_amdgcn_mfma_f32_16x16x32_bf16(pf[0][ks], vf[cd * 2 + ks],
                                                               o_acc[0][cd], 0, 0, 0);
        o_acc[1][cd] = __builtin_amdgcn_mfma_f32_16x16x32_bf16(pf[1][ks], vf[cd * 2 + ks],
                                                               o_acc[1][cd], 0, 0, 0);
      }
  };

  if (t0 < t1) {
    loadK(kfA, t0 * 64);
    int t = t0;
    while (true) {
      bool more = (t + 1 < t1);
      tile(kfA, kfB, t, more);
      if (!more) break;
      ++t;
      more = (t + 1 < t1);
      tile(kfB, kfA, t, more);
      if (!more) break;
      ++t;
    }
  }

  // epilogue: un-normalized partials + (m, l)
  u16* op = OP + split * OPSZ + (size_t)bh * NS * NHD;
#pragma unroll
  for (int qn = 0; qn < 2; ++qn) {
    float l = l_lane[qn];
    l += __shfl_xor(l, 16);
    l += __shfl_xor(l, 32);
#pragma unroll
    for (int cd = 0; cd < 4; ++cd) {
      int col = cd * 16 + r16;
#pragma unroll
      for (int j = 0; j < 4; ++j) {
        int row = q0w + qn * 16 + kg * 4 + j;
        op[(size_t)row * NHD + col] = f2bf(o_acc[qn][cd][j]);
      }
    }
    if (kg == 0)
      ML[(size_t)split * 32 * NS + (size_t)bh * NS + q0w + qn * 16 + r16] =
          make_float2(m_run[qn], l);
  }
}

// ---------------- combine the two KV-splits ----------------
__global__ __launch_bounds__(256) void attn_comb(const u16* __restrict__ OP,
                                                 const float2* __restrict__ ML,
                                                 u16* __restrict__ AO) {
  int idx = blockIdx.x * 256 + threadIdx.x;   // 524288
  int dg = (idx & 7) * 8;
  int q = (idx >> 3) & (NS - 1);
  int bh = idx >> 14;
  int b = bh >> 4, h = bh & 15;
  float2 ml0 = ML[(size_t)bh * NS + q];
  float2 ml1 = ML[(size_t)32 * NS + (size_t)bh * NS + q];
  float M = fmaxf(ml0.x, ml1.x);
  float w0 = exp2f(ml0.x - M), w1 = exp2f(ml1.x - M);
  float linv = 1.f / (ml0.y * w0 + ml1.y * w1);
  w0 *= linv;
  w1 *= linv;
  size_t src = ((size_t)bh * NS + q) * NHD + dg;
  uint4 r0 = *reinterpret_cast<const uint4*>(&OP[src]);
  uint4 r1 = *reinterpret_cast<const uint4*>(&OP[OPSZ + src]);
  const u16* e0 = reinterpret_cast<const u16*>(&r0);
  const u16* e1 = reinterpret_cast<const u16*>(&r1);
  u16 out[8];
#pragma unroll
  for (int j = 0; j < 8; ++j)
    out[j] = f2bf(bf2f(e0[j]) * w0 + bf2f(e1[j]) * w1);
  *reinterpret_cast<uint4*>(&AO[((size_t)b * NS + q) * ND + h * NHD + dg]) =
      *reinterpret_cast<uint4*>(out);
}

// ---------------- fused residual + LayerNorm ----------------
__global__ __launch_bounds__(256) void ln_kern(const float* __restrict__ a,
                                               const float* __restrict__ resid,
                                               const float* __restrict__ g,
                                               const float* __restrict__ bb,
                                               float* __restrict__ outf,
                                               u16* __restrict__ outb) {
  const int row = blockIdx.x;
  const int tid = threadIdx.x;
  const size_t off = (size_t)row * ND + tid * 4;
  f32x4 v = *reinterpret_cast<const f32x4*>(&a[off]);
  f32x4 r = *reinterpret_cast<const f32x4*>(&resid[off]);
#pragma unroll
  for (int j = 0; j < 4; ++j) v[j] += r[j];
  float s = v[0] + v[1] + v[2] + v[3];
  float s2 = v[0] * v[0] + v[1] * v[1] + v[2] * v[2] + v[3] * v[3];
#pragma unroll
  for (int m = 1; m < 64; m <<= 1) {
    s += __shfl_xor(s, m);
    s2 += __shfl_xor(s2, m);
  }
  __shared__ float ws1[4], ws2[4];
  int wave = tid >> 6, lane = tid & 63;
  if (lane == 0) { ws1[wave] = s; ws2[wave] = s2; }
  __syncthreads();
  s = ws1[0] + ws1[1] + ws1[2] + ws1[3];
  s2 = ws2[0] + ws2[1] + ws2[2] + ws2[3];
  float mean = s * (1.f / ND);
  float var = fmaxf(s2 * (1.f / ND) - mean * mean, 0.f);
  float rstd = rsqrtf(var + 1e-9f);
  f32x4 gg = *reinterpret_cast<const f32x4*>(&g[tid * 4]);
  f32x4 bv = *reinterpret_cast<const f32x4*>(&bb[tid * 4]);
  f32x4 o;
  u16x4 ob;
#pragma unroll
  for (int j = 0; j < 4; ++j) {
    o[j] = gg[j] * (v[j] - mean) * rstd + bv[j];
    ob[j] = f2bf(o[j]);
  }
  *reinterpret_cast<f32x4*>(&outf[off]) = o;
  *reinterpret_cast<u16x4*>(&outb[off]) = ob;
}

// ---------------- host launch ----------------
extern "C" void kernel_launch(void* const* d_in, const int* in_sizes, int n_in,
                              void* d_out, int out_size, void* d_ws, size_t ws_size,
                              hipStream_t stream) {
  const float* x = (const float*)d_in[0];
  const float* y = (const float*)d_in[1];
  const float* qkv_w = (const float*)d_in[3];
  const float* qkv_b = (const float*)d_in[4];
  const float* sa_fc_w = (const float*)d_in[5];
  const float* sa_fc_b = (const float*)d_in[6];
  const float* g1 = (const float*)d_in[7];
  const float* b1 = (const float*)d_in[8];
  const float* kv_w = (const float*)d_in[9];
  const float* kv_b = (const float*)d_in[10];
  const float* q_w = (const float*)d_in[11];
  const float* q_b = (const float*)d_in[12];
  const float* ca_fc_w = (const float*)d_in[13];
  const float* ca_fc_b = (const float*)d_in[14];
  const float* g2 = (const float*)d_in[15];
  const float* b2 = (const float*)d_in[16];
  const float* ff1_w = (const float*)d_in[17];
  const float* ff1_b = (const float*)d_in[18];
  const float* ff2_w = (const float*)d_in[19];
  const float* ff2_b = (const float*)d_in[20];
  const float* g3 = (const float*)d_in[21];
  const float* b3 = (const float*)d_in[22];

  if (ws_size < (120ull << 20)) return;

  char* w = (char*)d_ws;
  u16* W16 = (u16*)(w + 0);              // 8 MB weights (dead during attn -> ML lives here)
  u16* ACT = (u16*)(w + (8ull << 20));   // 8 MB activation (dead during attn -> OP split 0)
  u16* XB  = (u16*)(w + (16ull << 20));  // 8 MB x bf16 (dead during attn -> OP split 1)
  u16* Qb  = (u16*)(w + (24ull << 20));  // 8 MB cross-attn Q
  u16* VT  = (u16*)(w + (40ull << 20));  // 8 MB V^T [bh][64][S]
  u16* AO  = (u16*)(w + (48ull << 20));  // 8 MB attention out
  u16* G   = (u16*)(w + (56ull << 20));  // 24 MB big GEMM out
  float* Fa = (float*)(w + (88ull << 20));   // 16 MB
  float* Fb = (float*)(w + (104ull << 20));  // 16 MB
  u16* OPb = ACT;                        // OP partials: splits contiguous 8+16..24 MB
  float2* ML = (float2*)w;               // 1 MB, aliases W16
  float* OUT = (float*)d_out;

  dim3 wblk(32, 8);
  const int n4act = NBS * ND / 4;

  // ---- self attention block ----
  conv_bf16<<<n4act / 256, 256, 0, stream>>>(y, ACT, n4act);
  wconv_t<<<dim3(3 * ND / 32, ND / 32), wblk, 0, stream>>>(qkv_w, W16, ND, 3 * ND);
  gemm_bt<128, 0, 0><<<dim3(3 * ND / 128, NBS / 128), 256, 0, stream>>>(
      ACT, W16, qkv_b, nullptr, G, NBS, 3 * ND, ND);
  vt_kern<<<dim3(NS / 64, NB * NH), 256, 0, stream>>>(G, 3 * ND, 192, 128, VT);
  attn5<1><<<dim3(512, 2), 256, 0, stream>>>(G, 3 * ND, 192, G, 3 * ND, 192, 64, VT, OPb, ML);
  attn_comb<<<2048, 256, 0, stream>>>(OPb, ML, AO);
  wconv_t<<<dim3(ND / 32, ND / 32), wblk, 0, stream>>>(sa_fc_w, W16, ND, ND);
  gemm_bt<64, 1, 0><<<dim3(ND / 128, NBS / 64), 256, 0, stream>>>(
      AO, W16, sa_fc_b, Fa, nullptr, NBS, ND, ND);
  ln_kern<<<NBS, 256, 0, stream>>>(Fa, y, g1, b1, Fb, ACT);  // y1

  // ---- cross attention block ----
  conv_bf16<<<n4act / 256, 256, 0, stream>>>(x, XB, n4act);
  wconv_t<<<dim3(2 * ND / 32, ND / 32), wblk, 0, stream>>>(kv_w, W16, ND, 2 * ND);
  gemm_bt<128, 0, 0><<<dim3(2 * ND / 128, NBS / 128), 256, 0, stream>>>(
      XB, W16, kv_b, nullptr, G, NBS, 2 * ND, ND);
  vt_kern<<<dim3(NS / 64, NB * NH), 256, 0, stream>>>(G, 2 * ND, 128, 64, VT);
  wconv_t<<<dim3(ND / 32, ND / 32), wblk, 0, stream>>>(q_w, W16, ND, ND);
  gemm_bt<64, 0, 0><<<dim3(ND / 128, NBS / 64), 256, 0, stream>>>(
      ACT, W16, q_b, nullptr, Qb, NBS, ND, ND);
  attn5<0><<<dim3(512, 2), 256, 0, stream>>>(Qb, ND, 64, G, 2 * ND, 128, 0, VT, OPb, ML);
  attn_comb<<<2048, 256, 0, stream>>>(OPb, ML, AO);
  wconv_t<<<dim3(ND / 32, ND / 32), wblk, 0, stream>>>(ca_fc_w, W16, ND, ND);
  gemm_bt<64, 1, 0><<<dim3(ND / 128, NBS / 64), 256, 0, stream>>>(
      AO, W16, ca_fc_b, Fa, nullptr, NBS, ND, ND);
  ln_kern<<<NBS, 256, 0, stream>>>(Fa, Fb, g2, b2, Fb, ACT);  // y2

  // ---- FFN ----
  wconv_t<<<dim3(NFF / 32, ND / 32), wblk, 0, stream>>>(ff1_w, W16, ND, NFF);
  gemm_bt<128, 0, 1><<<dim3(NFF / 128, NBS / 128), 256, 0, stream>>>(
      ACT, W16, ff1_b, nullptr, G, NBS, NFF, ND);
  wconv_t<<<dim3(ND / 32, NFF / 32), wblk, 0, stream>>>(ff2_w, W16, NFF, ND);
  gemm_bt<64, 1, 0><<<dim3(ND / 128, NBS / 64), 256, 0, stream>>>(
      G, W16, ff2_b, Fa, nullptr, NBS, ND, NFF);
  ln_kern<<<NBS, 256, 0, stream>>>(Fa, Fb, g3, b3, OUT, ACT);
}

// Round 6
// 570.291 us; speedup vs baseline: 1.9231x; 1.9231x over previous
//
#include <hip/hip_runtime.h>

typedef unsigned short u16;
typedef unsigned int u32;
typedef __attribute__((ext_vector_type(4))) float f32x4;
typedef __attribute__((ext_vector_type(8))) __bf16 bf16x8;
typedef __attribute__((ext_vector_type(2))) __bf16 bf16x2;
typedef __attribute__((ext_vector_type(4))) u16 u16x4;

#define NB 2
#define NS 2048
#define ND 1024
#define NH 16
#define NHD 64
#define NFF 4096
#define NBS (NB * NS)   // 4096 rows

typedef const __attribute__((address_space(1))) unsigned int as1_u32;
typedef __attribute__((address_space(3))) unsigned int as3_u32;

__device__ __forceinline__ void gl_lds16(const u16* g, u16* l) {
  __builtin_amdgcn_global_load_lds((as1_u32*)g, (as3_u32*)l, 16, 0, 0);
}

__device__ __forceinline__ u16 f2bf(float f) {
  union { float f; unsigned u; } v; v.f = f;
  unsigned r = (v.u + 0x7FFFu + ((v.u >> 16) & 1u)) >> 16;  // RNE
  return (u16)r;
}

__device__ __forceinline__ float bf2f(u16 u) {
  union { u32 u; float f; } v; v.u = ((u32)u) << 16; return v.f;
}

__device__ __forceinline__ u32 pkbf(float a, float b) {
  bf16x2 v; v[0] = (__bf16)a; v[1] = (__bf16)b;
  union { bf16x2 v; u32 u; } c; c.v = v; return c.u;
}

// ---------------- f32 -> bf16 (vectorized) ----------------
__global__ __launch_bounds__(256) void conv_bf16(const float* __restrict__ in,
                                                 u16* __restrict__ out, int n4) {
  int i = blockIdx.x * 256 + threadIdx.x;
  if (i >= n4) return;
  f32x4 v = *reinterpret_cast<const f32x4*>(&in[(size_t)i * 4]);
  u16x4 o;
#pragma unroll
  for (int j = 0; j < 4; ++j) o[j] = f2bf(v[j]);
  *reinterpret_cast<u16x4*>(&out[(size_t)i * 4]) = o;
}

// ---------------- weight convert + transpose: [K,N] f32 -> [N,K] bf16 ----------------
__global__ void wconv_t(const float* __restrict__ in, u16* __restrict__ out, int K, int N) {
  __shared__ float t[32][33];
  int n0 = blockIdx.x * 32, k0 = blockIdx.y * 32;
  int tx = threadIdx.x, ty = threadIdx.y;  // 32 x 8
#pragma unroll
  for (int i = ty; i < 32; i += 8) t[i][tx] = in[(size_t)(k0 + i) * N + n0 + tx];
  __syncthreads();
#pragma unroll
  for (int i = ty; i < 32; i += 8)
    out[(size_t)(n0 + i) * K + k0 + tx] = f2bf(t[tx][i]);
}

// ---------------- GEMM, 2-phase double-buffered ----------------
template <int TM, int OUTF32, int RELU>
__global__ __launch_bounds__(256) void gemm_bt(const u16* __restrict__ A,
                                               const u16* __restrict__ BT,
                                               const float* __restrict__ bias,
                                               float* __restrict__ Cf,
                                               u16* __restrict__ Cb,
                                               int M, int N, int K) {
  constexpr int MR = TM / 32;
  constexpr int ACH = TM / 64;
  __shared__ __align__(16) u16 lA[2][TM * 32];
  __shared__ __align__(16) u16 lB[2][128 * 32];
  const int tid = threadIdx.x;
  const int lane = tid & 63, wave = tid >> 6;
  const int bm = blockIdx.y * TM, bn = blockIdx.x * 128;
  const int wr = (wave >> 1) * (MR * 16), wc = (wave & 1) * 64;
  const int r16 = lane & 15, kg = lane >> 4;

  f32x4 acc[MR][4] = {};

  auto stage = [&](int buf, int k0) {
#pragma unroll
    for (int c = 0; c < ACH; ++c) {
      int chunk = c * 256 + tid;
      int r = chunk >> 2, kc = (chunk & 3) * 8;
      gl_lds16(&A[(size_t)(bm + r) * K + k0 + kc], &lA[buf][(c * 256 + wave * 64) * 8]);
    }
#pragma unroll
    for (int c = 0; c < 2; ++c) {
      int chunk = c * 256 + tid;
      int r = chunk >> 2, kc = (chunk & 3) * 8;
      gl_lds16(&BT[(size_t)(bn + r) * K + k0 + kc], &lB[buf][(c * 256 + wave * 64) * 8]);
    }
  };

  stage(0, 0);
  __syncthreads();

  const int nk = K / 32;
  for (int i = 0; i < nk; ++i) {
    const int cur = i & 1;
    if (i + 1 < nk) stage(cur ^ 1, (i + 1) * 32);

    bf16x8 af[MR], bfr[4];
#pragma unroll
    for (int m = 0; m < MR; ++m)
      af[m] = *reinterpret_cast<const bf16x8*>(&lA[cur][(wr + m * 16 + r16) * 32 + kg * 8]);
#pragma unroll
    for (int n = 0; n < 4; ++n)
      bfr[n] = *reinterpret_cast<const bf16x8*>(&lB[cur][(wc + n * 16 + r16) * 32 + kg * 8]);
#pragma unroll
    for (int m = 0; m < MR; ++m)
#pragma unroll
      for (int n = 0; n < 4; ++n)
        acc[m][n] = __builtin_amdgcn_mfma_f32_16x16x32_bf16(af[m], bfr[n], acc[m][n], 0, 0, 0);

    __syncthreads();
  }

#pragma unroll
  for (int m = 0; m < MR; ++m) {
    int row = bm + wr + m * 16 + kg * 4;
#pragma unroll
    for (int n = 0; n < 4; ++n) {
      int col = bn + wc + n * 16 + r16;
      float bv = bias[col];
#pragma unroll
      for (int j = 0; j < 4; ++j) {
        float v = acc[m][n][j] + bv;
        if (RELU) v = fmaxf(v, 0.f);
        if (OUTF32)
          Cf[(size_t)(row + j) * N + col] = v;
        else
          Cb[(size_t)(row + j) * N + col] = f2bf(v);
      }
    }
  }
}

// ---------------- V transpose via LDS: 64x64 tiles ----------------
__global__ __launch_bounds__(256) void vt_kern(const u16* __restrict__ src, int stride,
                                               int hmul, int hadd, u16* __restrict__ VT) {
  __shared__ u16 lt[64][72];
  const int bh = blockIdx.y;
  const int b = bh >> 4, h = bh & 15;
  const int s0 = blockIdx.x * 64;
  const u16* sb = src + (size_t)b * NS * stride + h * hmul + hadd;
#pragma unroll
  for (int c = 0; c < 2; ++c) {
    int chunk = c * 256 + threadIdx.x;
    int r = chunk >> 3, d = (chunk & 7) * 8;
    *reinterpret_cast<uint4*>(&lt[r][d]) =
        *reinterpret_cast<const uint4*>(&sb[(size_t)(s0 + r) * stride + d]);
  }
  __syncthreads();
  const int d = threadIdx.x >> 2, sq = (threadIdx.x & 3) * 16;
  union { u16 e[16]; uint4 v[2]; } pk;
#pragma unroll
  for (int i = 0; i < 16; ++i) pk.e[i] = lt[sq + i][d];
  uint4* dst = reinterpret_cast<uint4*>(&VT[((size_t)bh * NHD + d) * NS + s0 + sq]);
  dst[0] = pk.v[0];
  dst[1] = pk.v[1];
}

// ---------------- flash attention v6: KV-split, TLP-driven, no spill ----------------
// grid (512, 2): 1024 blocks, 4096 waves -> ~16 waves/CU at VGPR<=128.
// Single kf buffer (K issued first, V second: QK^T waits only on K; V hides
// under QK+softmax). Lane-local softmax, gated rescale, deferred l-reduce.
#define LPP 72
#define C1F 0.180336880f  // 0.125 * log2(e)
#define OPSZ ((size_t)32 * NS * NHD)

template <int CAUSAL>
__global__ __launch_bounds__(256, 2) void attn6(const u16* __restrict__ Qp, int qstride,
                                                int qhm, const u16* __restrict__ Kp,
                                                int kstride, int khm, int kha,
                                                const u16* __restrict__ VT,
                                                u16* __restrict__ OP,
                                                float2* __restrict__ ML) {
  const int bid = blockIdx.x;              // 512
  const int split = blockIdx.y;            // 0/1
  const int xcd = bid & 7, j5 = bid >> 3;
  const int bh = xcd + 8 * (j5 >> 4);      // 4 bh per XCD
  int qt = j5 & 15;
  if (CAUSAL) qt = 15 - qt;                // heavy q-tiles first
  const int b = bh >> 4, h = bh & 15;
  const int tid = threadIdx.x, lane = tid & 63, wave = tid >> 6;
  const int r16 = lane & 15, kg = lane >> 4;
  const int q0w = qt * 128 + wave * 32;

  __shared__ __align__(16) u16 lP[4][32 * LPP];
  u16* lPw = &lP[wave][0];

  const u16* qb = Qp + (size_t)b * NS * qstride + h * qhm;
  const u16* kb = Kp + (size_t)b * NS * kstride + h * khm + kha;
  const u16* vb = VT + (size_t)bh * NHD * NS;

  bf16x8 qf[2][2];
#pragma unroll
  for (int qn = 0; qn < 2; ++qn)
#pragma unroll
    for (int ks = 0; ks < 2; ++ks)
      qf[qn][ks] = *reinterpret_cast<const bf16x8*>(
          &qb[(size_t)(q0w + qn * 16 + r16) * qstride + ks * 32 + kg * 8]);

  f32x4 o_acc[2][4] = {};
  float m_run[2] = {-1e30f, -1e30f}, l_lane[2] = {0.f, 0.f};

  const int ntw = CAUSAL ? (q0w / 64 + 1) : (NS / 64);
  const int half = (ntw + 1) >> 1;
  const int t0 = split ? half : 0;
  const int t1 = split ? ntw : half;

  for (int t = t0; t < t1; ++t) {
    const int kv0 = t * 64;
    bf16x8 kf[8], vf[8];
    // K issued first: QK^T waits only on these (vmcnt(8))
#pragma unroll
    for (int c = 0; c < 4; ++c)
#pragma unroll
      for (int ks = 0; ks < 2; ++ks)
        kf[c * 2 + ks] = *reinterpret_cast<const bf16x8*>(
            &kb[(size_t)(kv0 + c * 16 + r16) * kstride + ks * 32 + kg * 8]);
    // V issued second: consumed at PV (latency hides under QK + softmax)
#pragma unroll
    for (int cd = 0; cd < 4; ++cd)
#pragma unroll
      for (int ks = 0; ks < 2; ++ks)
        vf[cd * 2 + ks] = *reinterpret_cast<const bf16x8*>(
            &vb[(size_t)(cd * 16 + r16) * NS + kv0 + ks * 32 + kg * 8]);

    // S^T = K @ Q^T
    f32x4 s[2][4] = {};
#pragma unroll
    for (int c = 0; c < 4; ++c)
#pragma unroll
      for (int ks = 0; ks < 2; ++ks) {
        s[0][c] = __builtin_amdgcn_mfma_f32_16x16x32_bf16(kf[c * 2 + ks], qf[0][ks], s[0][c], 0, 0, 0);
        s[1][c] = __builtin_amdgcn_mfma_f32_16x16x32_bf16(kf[c * 2 + ks], qf[1][ks], s[1][c], 0, 0, 0);
      }

#pragma unroll
    for (int qn = 0; qn < 2; ++qn) {
      if (CAUSAL && t == ntw - 1) {
        const int q = q0w + qn * 16 + r16;
#pragma unroll
        for (int c = 0; c < 4; ++c)
#pragma unroll
          for (int j = 0; j < 4; ++j)
            if (kv0 + c * 16 + kg * 4 + j > q) s[qn][c][j] = -1e31f;
      }
      float mxr = s[qn][0][0];
#pragma unroll
      for (int c = 0; c < 4; ++c)
#pragma unroll
        for (int j = 0; j < 4; ++j) mxr = fmaxf(mxr, s[qn][c][j]);
      float mn = m_run[qn];
      if (!__all(mxr * C1F <= mn + 8.f)) {   // rescale: rare (defer-max T13)
        float mz = mxr * C1F;
        mz = fmaxf(mz, __shfl_xor(mz, 16));
        mz = fmaxf(mz, __shfl_xor(mz, 32));
        mn = fmaxf(m_run[qn], mz);
        const float cr = exp2f(m_run[qn] - mn);
        m_run[qn] = mn;
        l_lane[qn] *= cr;
        float crow[4];
#pragma unroll
        for (int j = 0; j < 4; ++j) crow[j] = __shfl(cr, kg * 4 + j);
#pragma unroll
        for (int cd = 0; cd < 4; ++cd)
#pragma unroll
          for (int j = 0; j < 4; ++j) o_acc[qn][cd][j] *= crow[j];
      }
      float su = 0.f;
#pragma unroll
      for (int c = 0; c < 4; ++c)
#pragma unroll
        for (int j = 0; j < 4; ++j) {
          float p = exp2f(fmaf(s[qn][c][j], C1F, -mn));
          s[qn][c][j] = p;
          su += p;
        }
      l_lane[qn] += su;

      // P -> wave-private LDS (b64 packed)
#pragma unroll
      for (int c = 0; c < 4; ++c) {
        uint2 w2 = {pkbf(s[qn][c][0], s[qn][c][1]), pkbf(s[qn][c][2], s[qn][c][3])};
        *reinterpret_cast<uint2*>(&lPw[(qn * 16 + r16) * LPP + c * 16 + kg * 4]) = w2;
      }
    }

    // PV
    bf16x8 pf[2][2];
#pragma unroll
    for (int qn = 0; qn < 2; ++qn)
#pragma unroll
      for (int ks = 0; ks < 2; ++ks)
        pf[qn][ks] = *reinterpret_cast<const bf16x8*>(
            &lPw[(qn * 16 + r16) * LPP + ks * 32 + kg * 8]);
#pragma unroll
    for (int cd = 0; cd < 4; ++cd)
#pragma unroll
      for (int ks = 0; ks < 2; ++ks) {
        o_acc[0][cd] = __builtin_amdgcn_mfma_f32_16x16x32_bf16(pf[0][ks], vf[cd * 2 + ks],
                                                               o_acc[0][cd], 0, 0, 0);
        o_acc[1][cd] = __builtin_amdgcn_mfma_f32_16x16x32_bf16(pf[1][ks], vf[cd * 2 + ks],
                                                               o_acc[1][cd], 0, 0, 0);
      }
  }

  // epilogue: un-normalized partials + (m, l)
  u16* op = OP + split * OPSZ + (size_t)bh * NS * NHD;
#pragma unroll
  for (int qn = 0; qn < 2; ++qn) {
    float l = l_lane[qn];
    l += __shfl_xor(l, 16);
    l += __shfl_xor(l, 32);
#pragma unroll
    for (int cd = 0; cd < 4; ++cd) {
      int col = cd * 16 + r16;
#pragma unroll
      for (int j = 0; j < 4; ++j) {
        int row = q0w + qn * 16 + kg * 4 + j;
        op[(size_t)row * NHD + col] = f2bf(o_acc[qn][cd][j]);
      }
    }
    if (kg == 0)
      ML[(size_t)split * 32 * NS + (size_t)bh * NS + q0w + qn * 16 + r16] =
          make_float2(m_run[qn], l);
  }
}

// ---------------- combine the two KV-splits ----------------
__global__ __launch_bounds__(256) void attn_comb(const u16* __restrict__ OP,
                                                 const float2* __restrict__ ML,
                                                 u16* __restrict__ AO) {
  int idx = blockIdx.x * 256 + threadIdx.x;   // 524288
  int dg = (idx & 7) * 8;
  int q = (idx >> 3) & (NS - 1);
  int bh = idx >> 14;
  int b = bh >> 4, h = bh & 15;
  float2 ml0 = ML[(size_t)bh * NS + q];
  float2 ml1 = ML[(size_t)32 * NS + (size_t)bh * NS + q];
  float M = fmaxf(ml0.x, ml1.x);
  float w0 = exp2f(ml0.x - M), w1 = exp2f(ml1.x - M);
  float linv = 1.f / (ml0.y * w0 + ml1.y * w1);
  w0 *= linv;
  w1 *= linv;
  size_t src = ((size_t)bh * NS + q) * NHD + dg;
  uint4 r0 = *reinterpret_cast<const uint4*>(&OP[src]);
  uint4 r1 = *reinterpret_cast<const uint4*>(&OP[OPSZ + src]);
  const u16* e0 = reinterpret_cast<const u16*>(&r0);
  const u16* e1 = reinterpret_cast<const u16*>(&r1);
  u16 out[8];
#pragma unroll
  for (int j = 0; j < 8; ++j)
    out[j] = f2bf(bf2f(e0[j]) * w0 + bf2f(e1[j]) * w1);
  *reinterpret_cast<uint4*>(&AO[((size_t)b * NS + q) * ND + h * NHD + dg]) =
      *reinterpret_cast<uint4*>(out);
}

// ---------------- fused residual + LayerNorm ----------------
__global__ __launch_bounds__(256) void ln_kern(const float* __restrict__ a,
                                               const float* __restrict__ resid,
                                               const float* __restrict__ g,
                                               const float* __restrict__ bb,
                                               float* __restrict__ outf,
                                               u16* __restrict__ outb) {
  const int row = blockIdx.x;
  const int tid = threadIdx.x;
  const size_t off = (size_t)row * ND + tid * 4;
  f32x4 v = *reinterpret_cast<const f32x4*>(&a[off]);
  f32x4 r = *reinterpret_cast<const f32x4*>(&resid[off]);
#pragma unroll
  for (int j = 0; j < 4; ++j) v[j] += r[j];
  float s = v[0] + v[1] + v[2] + v[3];
  float s2 = v[0] * v[0] + v[1] * v[1] + v[2] * v[2] + v[3] * v[3];
#pragma unroll
  for (int m = 1; m < 64; m <<= 1) {
    s += __shfl_xor(s, m);
    s2 += __shfl_xor(s2, m);
  }
  __shared__ float ws1[4], ws2[4];
  int wave = tid >> 6, lane = tid & 63;
  if (lane == 0) { ws1[wave] = s; ws2[wave] = s2; }
  __syncthreads();
  s = ws1[0] + ws1[1] + ws1[2] + ws1[3];
  s2 = ws2[0] + ws2[1] + ws2[2] + ws2[3];
  float mean = s * (1.f / ND);
  float var = fmaxf(s2 * (1.f / ND) - mean * mean, 0.f);
  float rstd = rsqrtf(var + 1e-9f);
  f32x4 gg = *reinterpret_cast<const f32x4*>(&g[tid * 4]);
  f32x4 bv = *reinterpret_cast<const f32x4*>(&bb[tid * 4]);
  f32x4 o;
  u16x4 ob;
#pragma unroll
  for (int j = 0; j < 4; ++j) {
    o[j] = gg[j] * (v[j] - mean) * rstd + bv[j];
    ob[j] = f2bf(o[j]);
  }
  *reinterpret_cast<f32x4*>(&outf[off]) = o;
  *reinterpret_cast<u16x4*>(&outb[off]) = ob;
}

// ---------------- host launch ----------------
extern "C" void kernel_launch(void* const* d_in, const int* in_sizes, int n_in,
                              void* d_out, int out_size, void* d_ws, size_t ws_size,
                              hipStream_t stream) {
  const float* x = (const float*)d_in[0];
  const float* y = (const float*)d_in[1];
  const float* qkv_w = (const float*)d_in[3];
  const float* qkv_b = (const float*)d_in[4];
  const float* sa_fc_w = (const float*)d_in[5];
  const float* sa_fc_b = (const float*)d_in[6];
  const float* g1 = (const float*)d_in[7];
  const float* b1 = (const float*)d_in[8];
  const float* kv_w = (const float*)d_in[9];
  const float* kv_b = (const float*)d_in[10];
  const float* q_w = (const float*)d_in[11];
  const float* q_b = (const float*)d_in[12];
  const float* ca_fc_w = (const float*)d_in[13];
  const float* ca_fc_b = (const float*)d_in[14];
  const float* g2 = (const float*)d_in[15];
  const float* b2 = (const float*)d_in[16];
  const float* ff1_w = (const float*)d_in[17];
  const float* ff1_b = (const float*)d_in[18];
  const float* ff2_w = (const float*)d_in[19];
  const float* ff2_b = (const float*)d_in[20];
  const float* g3 = (const float*)d_in[21];
  const float* b3 = (const float*)d_in[22];

  if (ws_size < (120ull << 20)) return;

  char* w = (char*)d_ws;
  u16* W16 = (u16*)(w + 0);              // 8 MB weights (ML aliases during attn)
  u16* ACT = (u16*)(w + (8ull << 20));   // 8 MB activation (OP split 0 aliases)
  u16* XB  = (u16*)(w + (16ull << 20));  // 8 MB x bf16 (OP split 1 aliases)
  u16* Qb  = (u16*)(w + (24ull << 20));  // 8 MB cross-attn Q
  u16* VT  = (u16*)(w + (40ull << 20));  // 8 MB V^T [bh][64][S]
  u16* AO  = (u16*)(w + (48ull << 20));  // 8 MB attention out
  u16* G   = (u16*)(w + (56ull << 20));  // 24 MB big GEMM out
  float* Fa = (float*)(w + (88ull << 20));   // 16 MB
  float* Fb = (float*)(w + (104ull << 20));  // 16 MB
  u16* OPb = ACT;
  float2* ML = (float2*)w;
  float* OUT = (float*)d_out;

  dim3 wblk(32, 8);
  const int n4act = NBS * ND / 4;

  // ---- self attention block ----
  conv_bf16<<<n4act / 256, 256, 0, stream>>>(y, ACT, n4act);
  wconv_t<<<dim3(3 * ND / 32, ND / 32), wblk, 0, stream>>>(qkv_w, W16, ND, 3 * ND);
  gemm_bt<128, 0, 0><<<dim3(3 * ND / 128, NBS / 128), 256, 0, stream>>>(
      ACT, W16, qkv_b, nullptr, G, NBS, 3 * ND, ND);
  vt_kern<<<dim3(NS / 64, NB * NH), 256, 0, stream>>>(G, 3 * ND, 192, 128, VT);
  attn6<1><<<dim3(512, 2), 256, 0, stream>>>(G, 3 * ND, 192, G, 3 * ND, 192, 64, VT, OPb, ML);
  attn_comb<<<2048, 256, 0, stream>>>(OPb, ML, AO);
  wconv_t<<<dim3(ND / 32, ND / 32), wblk, 0, stream>>>(sa_fc_w, W16, ND, ND);
  gemm_bt<64, 1, 0><<<dim3(ND / 128, NBS / 64), 256, 0, stream>>>(
      AO, W16, sa_fc_b, Fa, nullptr, NBS, ND, ND);
  ln_kern<<<NBS, 256, 0, stream>>>(Fa, y, g1, b1, Fb, ACT);  // y1

  // ---- cross attention block ----
  conv_bf16<<<n4act / 256, 256, 0, stream>>>(x, XB, n4act);
  wconv_t<<<dim3(2 * ND / 32, ND / 32), wblk, 0, stream>>>(kv_w, W16, ND, 2 * ND);
  gemm_bt<128, 0, 0><<<dim3(2 * ND / 128, NBS / 128), 256, 0, stream>>>(
      XB, W16, kv_b, nullptr, G, NBS, 2 * ND, ND);
  vt_kern<<<dim3(NS / 64, NB * NH), 256, 0, stream>>>(G, 2 * ND, 128, 64, VT);
  wconv_t<<<dim3(ND / 32, ND / 32), wblk, 0, stream>>>(q_w, W16, ND, ND);
  gemm_bt<64, 0, 0><<<dim3(ND / 128, NBS / 64), 256, 0, stream>>>(
      ACT, W16, q_b, nullptr, Qb, NBS, ND, ND);
  attn6<0><<<dim3(512, 2), 256, 0, stream>>>(Qb, ND, 64, G, 2 * ND, 128, 0, VT, OPb, ML);
  attn_comb<<<2048, 256, 0, stream>>>(OPb, ML, AO);
  wconv_t<<<dim3(ND / 32, ND / 32), wblk, 0, stream>>>(ca_fc_w, W16, ND, ND);
  gemm_bt<64, 1, 0><<<dim3(ND / 128, NBS / 64), 256, 0, stream>>>(
      AO, W16, ca_fc_b, Fa, nullptr, NBS, ND, ND);
  ln_kern<<<NBS, 256, 0, stream>>>(Fa, Fb, g2, b2, Fb, ACT);  // y2

  // ---- FFN ----
  wconv_t<<<dim3(NFF / 32, ND / 32), wblk, 0, stream>>>(ff1_w, W16, ND, NFF);
  gemm_bt<128, 0, 1><<<dim3(NFF / 128, NBS / 128), 256, 0, stream>>>(
      ACT, W16, ff1_b, nullptr, G, NBS, NFF, ND);
  wconv_t<<<dim3(ND / 32, NFF / 32), wblk, 0, stream>>>(ff2_w, W16, NFF, ND);
  gemm_bt<64, 1, 0><<<dim3(ND / 128, NBS / 64), 256, 0, stream>>>(
      G, W16, ff2_b, Fa, nullptr, NBS, ND, NFF);
  ln_kern<<<NBS, 256, 0, stream>>>(Fa, Fb, g3, b3, OUT, ACT);
}

// Round 7
// 521.798 us; speedup vs baseline: 2.1018x; 1.0929x over previous
//
#include <hip/hip_runtime.h>

typedef unsigned short u16;
typedef unsigned int u32;
typedef __attribute__((ext_vector_type(4))) float f32x4;
typedef __attribute__((ext_vector_type(8))) __bf16 bf16x8;
typedef __attribute__((ext_vector_type(2))) __bf16 bf16x2;
typedef __attribute__((ext_vector_type(4))) u16 u16x4;

#define NB 2
#define NS 2048
#define ND 1024
#define NH 16
#define NHD 64
#define NFF 4096
#define NBS (NB * NS)   // 4096 rows

typedef const __attribute__((address_space(1))) unsigned int as1_u32;
typedef __attribute__((address_space(3))) unsigned int as3_u32;

__device__ __forceinline__ void gl_lds16(const u16* g, u16* l) {
  __builtin_amdgcn_global_load_lds((as1_u32*)g, (as3_u32*)l, 16, 0, 0);
}

__device__ __forceinline__ u16 f2bf(float f) {
  union { float f; unsigned u; } v; v.f = f;
  unsigned r = (v.u + 0x7FFFu + ((v.u >> 16) & 1u)) >> 16;  // RNE
  return (u16)r;
}

__device__ __forceinline__ float bf2f(u16 u) {
  union { u32 u; float f; } v; v.u = ((u32)u) << 16; return v.f;
}

__device__ __forceinline__ u32 pkbf(float a, float b) {
  bf16x2 v; v[0] = (__bf16)a; v[1] = (__bf16)b;
  union { bf16x2 v; u32 u; } c; c.v = v; return c.u;
}

// ---------------- f32 -> bf16 (vectorized) ----------------
__global__ __launch_bounds__(256) void conv_bf16(const float* __restrict__ in,
                                                 u16* __restrict__ out, int n4) {
  int i = blockIdx.x * 256 + threadIdx.x;
  if (i >= n4) return;
  f32x4 v = *reinterpret_cast<const f32x4*>(&in[(size_t)i * 4]);
  u16x4 o;
#pragma unroll
  for (int j = 0; j < 4; ++j) o[j] = f2bf(v[j]);
  *reinterpret_cast<u16x4*>(&out[(size_t)i * 4]) = o;
}

// ---------------- weight convert + transpose: [K,N] f32 -> [N,K] bf16 ----------------
__global__ void wconv_t(const float* __restrict__ in, u16* __restrict__ out, int K, int N) {
  __shared__ float t[32][33];
  int n0 = blockIdx.x * 32, k0 = blockIdx.y * 32;
  int tx = threadIdx.x, ty = threadIdx.y;  // 32 x 8
#pragma unroll
  for (int i = ty; i < 32; i += 8) t[i][tx] = in[(size_t)(k0 + i) * N + n0 + tx];
  __syncthreads();
#pragma unroll
  for (int i = ty; i < 32; i += 8)
    out[(size_t)(n0 + i) * K + k0 + tx] = f2bf(t[tx][i]);
}

// ---------------- GEMM, 2-phase double-buffered ----------------
template <int TM, int OUTF32, int RELU>
__global__ __launch_bounds__(256) void gemm_bt(const u16* __restrict__ A,
                                               const u16* __restrict__ BT,
                                               const float* __restrict__ bias,
                                               float* __restrict__ Cf,
                                               u16* __restrict__ Cb,
                                               int M, int N, int K) {
  constexpr int MR = TM / 32;
  constexpr int ACH = TM / 64;
  __shared__ __align__(16) u16 lA[2][TM * 32];
  __shared__ __align__(16) u16 lB[2][128 * 32];
  const int tid = threadIdx.x;
  const int lane = tid & 63, wave = tid >> 6;
  const int bm = blockIdx.y * TM, bn = blockIdx.x * 128;
  const int wr = (wave >> 1) * (MR * 16), wc = (wave & 1) * 64;
  const int r16 = lane & 15, kg = lane >> 4;

  f32x4 acc[MR][4] = {};

  auto stage = [&](int buf, int k0) {
#pragma unroll
    for (int c = 0; c < ACH; ++c) {
      int chunk = c * 256 + tid;
      int r = chunk >> 2, kc = (chunk & 3) * 8;
      gl_lds16(&A[(size_t)(bm + r) * K + k0 + kc], &lA[buf][(c * 256 + wave * 64) * 8]);
    }
#pragma unroll
    for (int c = 0; c < 2; ++c) {
      int chunk = c * 256 + tid;
      int r = chunk >> 2, kc = (chunk & 3) * 8;
      gl_lds16(&BT[(size_t)(bn + r) * K + k0 + kc], &lB[buf][(c * 256 + wave * 64) * 8]);
    }
  };

  stage(0, 0);
  __syncthreads();

  const int nk = K / 32;
  for (int i = 0; i < nk; ++i) {
    const int cur = i & 1;
    if (i + 1 < nk) stage(cur ^ 1, (i + 1) * 32);

    bf16x8 af[MR], bfr[4];
#pragma unroll
    for (int m = 0; m < MR; ++m)
      af[m] = *reinterpret_cast<const bf16x8*>(&lA[cur][(wr + m * 16 + r16) * 32 + kg * 8]);
#pragma unroll
    for (int n = 0; n < 4; ++n)
      bfr[n] = *reinterpret_cast<const bf16x8*>(&lB[cur][(wc + n * 16 + r16) * 32 + kg * 8]);
#pragma unroll
    for (int m = 0; m < MR; ++m)
#pragma unroll
      for (int n = 0; n < 4; ++n)
        acc[m][n] = __builtin_amdgcn_mfma_f32_16x16x32_bf16(af[m], bfr[n], acc[m][n], 0, 0, 0);

    __syncthreads();
  }

#pragma unroll
  for (int m = 0; m < MR; ++m) {
    int row = bm + wr + m * 16 + kg * 4;
#pragma unroll
    for (int n = 0; n < 4; ++n) {
      int col = bn + wc + n * 16 + r16;
      float bv = bias[col];
#pragma unroll
      for (int j = 0; j < 4; ++j) {
        float v = acc[m][n][j] + bv;
        if (RELU) v = fmaxf(v, 0.f);
        if (OUTF32)
          Cf[(size_t)(row + j) * N + col] = v;
        else
          Cb[(size_t)(row + j) * N + col] = f2bf(v);
      }
    }
  }
}

// ---------------- V transpose via LDS: 64x64 tiles ----------------
__global__ __launch_bounds__(256) void vt_kern(const u16* __restrict__ src, int stride,
                                               int hmul, int hadd, u16* __restrict__ VT) {
  __shared__ u16 lt[64][72];
  const int bh = blockIdx.y;
  const int b = bh >> 4, h = bh & 15;
  const int s0 = blockIdx.x * 64;
  const u16* sb = src + (size_t)b * NS * stride + h * hmul + hadd;
#pragma unroll
  for (int c = 0; c < 2; ++c) {
    int chunk = c * 256 + threadIdx.x;
    int r = chunk >> 3, d = (chunk & 7) * 8;
    *reinterpret_cast<uint4*>(&lt[r][d]) =
        *reinterpret_cast<const uint4*>(&sb[(size_t)(s0 + r) * stride + d]);
  }
  __syncthreads();
  const int d = threadIdx.x >> 2, sq = (threadIdx.x & 3) * 16;
  union { u16 e[16]; uint4 v[2]; } pk;
#pragma unroll
  for (int i = 0; i < 16; ++i) pk.e[i] = lt[sq + i][d];
  uint4* dst = reinterpret_cast<uint4*>(&VT[((size_t)bh * NHD + d) * NS + s0 + sq]);
  dst[0] = pk.v[0];
  dst[1] = pk.v[1];
}

// ---------------- flash attention v7: block-cooperative LDS-staged K/V ----------------
// grid (512, 2). 4 waves stage K,V^T tiles into double-buffered LDS ONCE per block
// (4x less L2 traffic); reg-staged (issue-early/write-late) so next tile's latency
// hides under current compute. One barrier per tile; block-uniform loop bounds with
// wave-level compute predicate (causal trip counts differ per wave).
#define LKP 72
#define C1F 0.180336880f  // 0.125 * log2(e)
#define OPSZ ((size_t)32 * NS * NHD)

template <int CAUSAL>
__global__ __launch_bounds__(256) void attn7(const u16* __restrict__ Qp, int qstride,
                                             int qhm, const u16* __restrict__ Kp,
                                             int kstride, int khm, int kha,
                                             const u16* __restrict__ VT,
                                             u16* __restrict__ OP,
                                             float2* __restrict__ ML) {
  const int bid = blockIdx.x;              // 512
  const int split = blockIdx.y;            // 0/1
  const int xcd = bid & 7, j5 = bid >> 3;
  const int bh = xcd + 8 * (j5 >> 4);      // 4 bh per XCD
  int qt = j5 & 15;
  if (CAUSAL) qt = 15 - qt;                // heavy q-tiles first
  const int b = bh >> 4, h = bh & 15;
  const int tid = threadIdx.x, lane = tid & 63, wave = tid >> 6;
  const int r16 = lane & 15, kg = lane >> 4;
  const int q0w = qt * 128 + wave * 32;

  __shared__ __align__(16) u16 lK[2][64 * LKP];
  __shared__ __align__(16) u16 lV[2][64 * LKP];
  __shared__ __align__(16) u16 lP[4][32 * LKP];
  u16* lPw = &lP[wave][0];

  const u16* qb = Qp + (size_t)b * NS * qstride + h * qhm;
  const u16* kb = Kp + (size_t)b * NS * kstride + h * khm + kha;
  const u16* vb = VT + (size_t)bh * NHD * NS;

  // staging split: thread covers rows (tid>>3) and (tid>>3)+32, 16B col chunk
  const int srow = tid >> 3;
  const int scol = (tid & 7) * 8;

  bf16x8 qf[2][2];
#pragma unroll
  for (int qn = 0; qn < 2; ++qn)
#pragma unroll
    for (int ks = 0; ks < 2; ++ks)
      qf[qn][ks] = *reinterpret_cast<const bf16x8*>(
          &qb[(size_t)(q0w + qn * 16 + r16) * qstride + ks * 32 + kg * 8]);

  f32x4 o_acc[2][4] = {};
  float m_run[2] = {-1e30f, -1e30f}, l_lane[2] = {0.f, 0.f};

  // block-uniform tile range; wave-level compute bound
  const int ntb = CAUSAL ? (2 * qt + 2) : (NS / 64);        // block tiles
  const int wnt = CAUSAL ? (q0w / 64 + 1) : (NS / 64);      // wave tiles
  const int halfb = (ntb + 1) >> 1;
  const int t0 = split ? halfb : 0;
  const int t1 = split ? ntb : halfb;

  uint4 kreg[2], vreg[2];
  auto ldregs = [&](int t) {
    const int kv0 = t * 64;
#pragma unroll
    for (int c = 0; c < 2; ++c) {
      kreg[c] = *reinterpret_cast<const uint4*>(
          &kb[(size_t)(kv0 + srow + c * 32) * kstride + scol]);
      vreg[c] = *reinterpret_cast<const uint4*>(
          &vb[(size_t)(srow + c * 32) * NS + kv0 + scol]);
    }
  };
  auto wrlds = [&](int buf) {
#pragma unroll
    for (int c = 0; c < 2; ++c) {
      *reinterpret_cast<uint4*>(&lK[buf][(srow + c * 32) * LKP + scol]) = kreg[c];
      *reinterpret_cast<uint4*>(&lV[buf][(srow + c * 32) * LKP + scol]) = vreg[c];
    }
  };

  ldregs(t0);
  wrlds(0);
  __syncthreads();

  for (int t = t0; t < t1; ++t) {
    const int cur = (t - t0) & 1;
    const bool more = (t + 1 < t1);
    if (more) ldregs(t + 1);   // global loads in flight during compute

    if (t < wnt) {
      const int kv0 = t * 64;
      const u16* lKc = &lK[cur][0];
      const u16* lVc = &lV[cur][0];

      bf16x8 kf[8];
#pragma unroll
      for (int c = 0; c < 4; ++c)
#pragma unroll
        for (int ks = 0; ks < 2; ++ks)
          kf[c * 2 + ks] = *reinterpret_cast<const bf16x8*>(
              &lKc[(c * 16 + r16) * LKP + ks * 32 + kg * 8]);

      f32x4 s[2][4] = {};
#pragma unroll
      for (int c = 0; c < 4; ++c)
#pragma unroll
        for (int ks = 0; ks < 2; ++ks) {
          s[0][c] = __builtin_amdgcn_mfma_f32_16x16x32_bf16(kf[c * 2 + ks], qf[0][ks], s[0][c], 0, 0, 0);
          s[1][c] = __builtin_amdgcn_mfma_f32_16x16x32_bf16(kf[c * 2 + ks], qf[1][ks], s[1][c], 0, 0, 0);
        }

      // V frag reads issued now: ds latency overlaps softmax VALU
      bf16x8 vf[8];
#pragma unroll
      for (int cd = 0; cd < 4; ++cd)
#pragma unroll
        for (int ks = 0; ks < 2; ++ks)
          vf[cd * 2 + ks] = *reinterpret_cast<const bf16x8*>(
              &lVc[(cd * 16 + r16) * LKP + ks * 32 + kg * 8]);

#pragma unroll
      for (int qn = 0; qn < 2; ++qn) {
        if (CAUSAL && t == wnt - 1) {
          const int q = q0w + qn * 16 + r16;
#pragma unroll
          for (int c = 0; c < 4; ++c)
#pragma unroll
            for (int j = 0; j < 4; ++j)
              if (kv0 + c * 16 + kg * 4 + j > q) s[qn][c][j] = -1e31f;
        }
        float mxr = s[qn][0][0];
#pragma unroll
        for (int c = 0; c < 4; ++c)
#pragma unroll
          for (int j = 0; j < 4; ++j) mxr = fmaxf(mxr, s[qn][c][j]);
        float mn = m_run[qn];
        if (!__all(mxr * C1F <= mn + 8.f)) {   // rescale: rare (defer-max T13)
          float mz = mxr * C1F;
          mz = fmaxf(mz, __shfl_xor(mz, 16));
          mz = fmaxf(mz, __shfl_xor(mz, 32));
          mn = fmaxf(m_run[qn], mz);
          const float cr = exp2f(m_run[qn] - mn);
          m_run[qn] = mn;
          l_lane[qn] *= cr;
          float crow[4];
#pragma unroll
          for (int j = 0; j < 4; ++j) crow[j] = __shfl(cr, kg * 4 + j);
#pragma unroll
          for (int cd = 0; cd < 4; ++cd)
#pragma unroll
            for (int j = 0; j < 4; ++j) o_acc[qn][cd][j] *= crow[j];
        }
        float su = 0.f;
#pragma unroll
        for (int c = 0; c < 4; ++c)
#pragma unroll
          for (int j = 0; j < 4; ++j) {
            float p = exp2f(fmaf(s[qn][c][j], C1F, -mn));
            s[qn][c][j] = p;
            su += p;
          }
        l_lane[qn] += su;

#pragma unroll
        for (int c = 0; c < 4; ++c) {
          uint2 w2 = {pkbf(s[qn][c][0], s[qn][c][1]), pkbf(s[qn][c][2], s[qn][c][3])};
          *reinterpret_cast<uint2*>(&lPw[(qn * 16 + r16) * LKP + c * 16 + kg * 4]) = w2;
        }
      }

      bf16x8 pf[2][2];
#pragma unroll
      for (int qn = 0; qn < 2; ++qn)
#pragma unroll
        for (int ks = 0; ks < 2; ++ks)
          pf[qn][ks] = *reinterpret_cast<const bf16x8*>(
              &lPw[(qn * 16 + r16) * LKP + ks * 32 + kg * 8]);
#pragma unroll
      for (int cd = 0; cd < 4; ++cd)
#pragma unroll
        for (int ks = 0; ks < 2; ++ks) {
          o_acc[0][cd] = __builtin_amdgcn_mfma_f32_16x16x32_bf16(pf[0][ks], vf[cd * 2 + ks],
                                                                 o_acc[0][cd], 0, 0, 0);
          o_acc[1][cd] = __builtin_amdgcn_mfma_f32_16x16x32_bf16(pf[1][ks], vf[cd * 2 + ks],
                                                                 o_acc[1][cd], 0, 0, 0);
        }
    }

    if (more) wrlds(cur ^ 1);  // waits vmcnt via register dependency
    __syncthreads();           // one barrier per tile
  }

  // epilogue: un-normalized partials + (m, l)
  u16* op = OP + split * OPSZ + (size_t)bh * NS * NHD;
#pragma unroll
  for (int qn = 0; qn < 2; ++qn) {
    float l = l_lane[qn];
    l += __shfl_xor(l, 16);
    l += __shfl_xor(l, 32);
#pragma unroll
    for (int cd = 0; cd < 4; ++cd) {
      int col = cd * 16 + r16;
#pragma unroll
      for (int j = 0; j < 4; ++j) {
        int row = q0w + qn * 16 + kg * 4 + j;
        op[(size_t)row * NHD + col] = f2bf(o_acc[qn][cd][j]);
      }
    }
    if (kg == 0)
      ML[(size_t)split * 32 * NS + (size_t)bh * NS + q0w + qn * 16 + r16] =
          make_float2(m_run[qn], l);
  }
}

// ---------------- combine the two KV-splits ----------------
__global__ __launch_bounds__(256) void attn_comb(const u16* __restrict__ OP,
                                                 const float2* __restrict__ ML,
                                                 u16* __restrict__ AO) {
  int idx = blockIdx.x * 256 + threadIdx.x;   // 524288
  int dg = (idx & 7) * 8;
  int q = (idx >> 3) & (NS - 1);
  int bh = idx >> 14;
  int b = bh >> 4, h = bh & 15;
  float2 ml0 = ML[(size_t)bh * NS + q];
  float2 ml1 = ML[(size_t)32 * NS + (size_t)bh * NS + q];
  float M = fmaxf(ml0.x, ml1.x);
  float w0 = exp2f(ml0.x - M), w1 = exp2f(ml1.x - M);
  float linv = 1.f / (ml0.y * w0 + ml1.y * w1);
  w0 *= linv;
  w1 *= linv;
  size_t src = ((size_t)bh * NS + q) * NHD + dg;
  uint4 r0 = *reinterpret_cast<const uint4*>(&OP[src]);
  uint4 r1 = *reinterpret_cast<const uint4*>(&OP[OPSZ + src]);
  const u16* e0 = reinterpret_cast<const u16*>(&r0);
  const u16* e1 = reinterpret_cast<const u16*>(&r1);
  u16 out[8];
#pragma unroll
  for (int j = 0; j < 8; ++j)
    out[j] = f2bf(bf2f(e0[j]) * w0 + bf2f(e1[j]) * w1);
  *reinterpret_cast<uint4*>(&AO[((size_t)b * NS + q) * ND + h * NHD + dg]) =
      *reinterpret_cast<uint4*>(out);
}

// ---------------- fused residual + LayerNorm ----------------
__global__ __launch_bounds__(256) void ln_kern(const float* __restrict__ a,
                                               const float* __restrict__ resid,
                                               const float* __restrict__ g,
                                               const float* __restrict__ bb,
                                               float* __restrict__ outf,
                                               u16* __restrict__ outb) {
  const int row = blockIdx.x;
  const int tid = threadIdx.x;
  const size_t off = (size_t)row * ND + tid * 4;
  f32x4 v = *reinterpret_cast<const f32x4*>(&a[off]);
  f32x4 r = *reinterpret_cast<const f32x4*>(&resid[off]);
#pragma unroll
  for (int j = 0; j < 4; ++j) v[j] += r[j];
  float s = v[0] + v[1] + v[2] + v[3];
  float s2 = v[0] * v[0] + v[1] * v[1] + v[2] * v[2] + v[3] * v[3];
#pragma unroll
  for (int m = 1; m < 64; m <<= 1) {
    s += __shfl_xor(s, m);
    s2 += __shfl_xor(s2, m);
  }
  __shared__ float ws1[4], ws2[4];
  int wave = tid >> 6, lane = tid & 63;
  if (lane == 0) { ws1[wave] = s; ws2[wave] = s2; }
  __syncthreads();
  s = ws1[0] + ws1[1] + ws1[2] + ws1[3];
  s2 = ws2[0] + ws2[1] + ws2[2] + ws2[3];
  float mean = s * (1.f / ND);
  float var = fmaxf(s2 * (1.f / ND) - mean * mean, 0.f);
  float rstd = rsqrtf(var + 1e-9f);
  f32x4 gg = *reinterpret_cast<const f32x4*>(&g[tid * 4]);
  f32x4 bv = *reinterpret_cast<const f32x4*>(&bb[tid * 4]);
  f32x4 o;
  u16x4 ob;
#pragma unroll
  for (int j = 0; j < 4; ++j) {
    o[j] = gg[j] * (v[j] - mean) * rstd + bv[j];
    ob[j] = f2bf(o[j]);
  }
  *reinterpret_cast<f32x4*>(&outf[off]) = o;
  *reinterpret_cast<u16x4*>(&outb[off]) = ob;
}

// ---------------- host launch ----------------
extern "C" void kernel_launch(void* const* d_in, const int* in_sizes, int n_in,
                              void* d_out, int out_size, void* d_ws, size_t ws_size,
                              hipStream_t stream) {
  const float* x = (const float*)d_in[0];
  const float* y = (const float*)d_in[1];
  const float* qkv_w = (const float*)d_in[3];
  const float* qkv_b = (const float*)d_in[4];
  const float* sa_fc_w = (const float*)d_in[5];
  const float* sa_fc_b = (const float*)d_in[6];
  const float* g1 = (const float*)d_in[7];
  const float* b1 = (const float*)d_in[8];
  const float* kv_w = (const float*)d_in[9];
  const float* kv_b = (const float*)d_in[10];
  const float* q_w = (const float*)d_in[11];
  const float* q_b = (const float*)d_in[12];
  const float* ca_fc_w = (const float*)d_in[13];
  const float* ca_fc_b = (const float*)d_in[14];
  const float* g2 = (const float*)d_in[15];
  const float* b2 = (const float*)d_in[16];
  const float* ff1_w = (const float*)d_in[17];
  const float* ff1_b = (const float*)d_in[18];
  const float* ff2_w = (const float*)d_in[19];
  const float* ff2_b = (const float*)d_in[20];
  const float* g3 = (const float*)d_in[21];
  const float* b3 = (const float*)d_in[22];

  if (ws_size < (120ull << 20)) return;

  char* w = (char*)d_ws;
  u16* W16 = (u16*)(w + 0);              // 8 MB weights (ML aliases during attn)
  u16* ACT = (u16*)(w + (8ull << 20));   // 8 MB activation (OP split 0 aliases)
  u16* XB  = (u16*)(w + (16ull << 20));  // 8 MB x bf16 (OP split 1 aliases)
  u16* Qb  = (u16*)(w + (24ull << 20));  // 8 MB cross-attn Q
  u16* VT  = (u16*)(w + (40ull << 20));  // 8 MB V^T [bh][64][S]
  u16* AO  = (u16*)(w + (48ull << 20));  // 8 MB attention out
  u16* G   = (u16*)(w + (56ull << 20));  // 24 MB big GEMM out
  float* Fa = (float*)(w + (88ull << 20));   // 16 MB
  float* Fb = (float*)(w + (104ull << 20));  // 16 MB
  u16* OPb = ACT;
  float2* ML = (float2*)w;
  float* OUT = (float*)d_out;

  dim3 wblk(32, 8);
  const int n4act = NBS * ND / 4;

  // ---- self attention block ----
  conv_bf16<<<n4act / 256, 256, 0, stream>>>(y, ACT, n4act);
  wconv_t<<<dim3(3 * ND / 32, ND / 32), wblk, 0, stream>>>(qkv_w, W16, ND, 3 * ND);
  gemm_bt<128, 0, 0><<<dim3(3 * ND / 128, NBS / 128), 256, 0, stream>>>(
      ACT, W16, qkv_b, nullptr, G, NBS, 3 * ND, ND);
  vt_kern<<<dim3(NS / 64, NB * NH), 256, 0, stream>>>(G, 3 * ND, 192, 128, VT);
  attn7<1><<<dim3(512, 2), 256, 0, stream>>>(G, 3 * ND, 192, G, 3 * ND, 192, 64, VT, OPb, ML);
  attn_comb<<<2048, 256, 0, stream>>>(OPb, ML, AO);
  wconv_t<<<dim3(ND / 32, ND / 32), wblk, 0, stream>>>(sa_fc_w, W16, ND, ND);
  gemm_bt<64, 1, 0><<<dim3(ND / 128, NBS / 64), 256, 0, stream>>>(
      AO, W16, sa_fc_b, Fa, nullptr, NBS, ND, ND);
  ln_kern<<<NBS, 256, 0, stream>>>(Fa, y, g1, b1, Fb, ACT);  // y1

  // ---- cross attention block ----
  conv_bf16<<<n4act / 256, 256, 0, stream>>>(x, XB, n4act);
  wconv_t<<<dim3(2 * ND / 32, ND / 32), wblk, 0, stream>>>(kv_w, W16, ND, 2 * ND);
  gemm_bt<128, 0, 0><<<dim3(2 * ND / 128, NBS / 128), 256, 0, stream>>>(
      XB, W16, kv_b, nullptr, G, NBS, 2 * ND, ND);
  vt_kern<<<dim3(NS / 64, NB * NH), 256, 0, stream>>>(G, 2 * ND, 128, 64, VT);
  wconv_t<<<dim3(ND / 32, ND / 32), wblk, 0, stream>>>(q_w, W16, ND, ND);
  gemm_bt<64, 0, 0><<<dim3(ND / 128, NBS / 64), 256, 0, stream>>>(
      ACT, W16, q_b, nullptr, Qb, NBS, ND, ND);
  attn7<0><<<dim3(512, 2), 256, 0, stream>>>(Qb, ND, 64, G, 2 * ND, 128, 0, VT, OPb, ML);
  attn_comb<<<2048, 256, 0, stream>>>(OPb, ML, AO);
  wconv_t<<<dim3(ND / 32, ND / 32), wblk, 0, stream>>>(ca_fc_w, W16, ND, ND);
  gemm_bt<64, 1, 0><<<dim3(ND / 128, NBS / 64), 256, 0, stream>>>(
      AO, W16, ca_fc_b, Fa, nullptr, NBS, ND, ND);
  ln_kern<<<NBS, 256, 0, stream>>>(Fa, Fb, g2, b2, Fb, ACT);  // y2

  // ---- FFN ----
  wconv_t<<<dim3(NFF / 32, ND / 32), wblk, 0, stream>>>(ff1_w, W16, ND, NFF);
  gemm_bt<128, 0, 1><<<dim3(NFF / 128, NBS / 128), 256, 0, stream>>>(
      ACT, W16, ff1_b, nullptr, G, NBS, NFF, ND);
  wconv_t<<<dim3(ND / 32, NFF / 32), wblk, 0, stream>>>(ff2_w, W16, NFF, ND);
  gemm_bt<64, 1, 0><<<dim3(ND / 128, NBS / 64), 256, 0, stream>>>(
      G, W16, ff2_b, Fa, nullptr, NBS, ND, NFF);
  ln_kern<<<NBS, 256, 0, stream>>>(Fa, Fb, g3, b3, OUT, ACT);
}

// Round 8
// 518.136 us; speedup vs baseline: 2.1167x; 1.0071x over previous
//
#include <hip/hip_runtime.h>

typedef unsigned short u16;
typedef unsigned int u32;
typedef __attribute__((ext_vector_type(4))) float f32x4;
typedef __attribute__((ext_vector_type(8))) __bf16 bf16x8;
typedef __attribute__((ext_vector_type(2))) __bf16 bf16x2;
typedef __attribute__((ext_vector_type(4))) u16 u16x4;

#define NB 2
#define NS 2048
#define ND 1024
#define NH 16
#define NHD 64
#define NFF 4096
#define NBS (NB * NS)   // 4096 rows

typedef const __attribute__((address_space(1))) unsigned int as1_u32;
typedef __attribute__((address_space(3))) unsigned int as3_u32;

__device__ __forceinline__ void gl_lds16(const u16* g, u16* l) {
  __builtin_amdgcn_global_load_lds((as1_u32*)g, (as3_u32*)l, 16, 0, 0);
}

__device__ __forceinline__ u16 f2bf(float f) {
  union { float f; unsigned u; } v; v.f = f;
  unsigned r = (v.u + 0x7FFFu + ((v.u >> 16) & 1u)) >> 16;  // RNE
  return (u16)r;
}

__device__ __forceinline__ float bf2f(u16 u) {
  union { u32 u; float f; } v; v.u = ((u32)u) << 16; return v.f;
}

__device__ __forceinline__ u32 pkbf(float a, float b) {
  bf16x2 v; v[0] = (__bf16)a; v[1] = (__bf16)b;
  union { bf16x2 v; u32 u; } c; c.v = v; return c.u;
}

// XOR-swizzled LDS addressing (pitch 128B): bank-conflict-free for row-strided
// b128 fragment reads; XOR flips only bit 4 so 8B/16B alignment is preserved.
__device__ __forceinline__ char* lswz(void* base, int row, int bcol) {
  return (char*)base + row * 128 + (bcol ^ ((row & 7) << 4));
}
__device__ __forceinline__ const char* lswz(const void* base, int row, int bcol) {
  return (const char*)base + row * 128 + (bcol ^ ((row & 7) << 4));
}

// ---------------- f32 -> bf16 (vectorized) ----------------
__global__ __launch_bounds__(256) void conv_bf16(const float* __restrict__ in,
                                                 u16* __restrict__ out, int n4) {
  int i = blockIdx.x * 256 + threadIdx.x;
  if (i >= n4) return;
  f32x4 v = *reinterpret_cast<const f32x4*>(&in[(size_t)i * 4]);
  u16x4 o;
#pragma unroll
  for (int j = 0; j < 4; ++j) o[j] = f2bf(v[j]);
  *reinterpret_cast<u16x4*>(&out[(size_t)i * 4]) = o;
}

// ---------------- weight convert + transpose: [K,N] f32 -> [N,K] bf16 ----------------
__global__ void wconv_t(const float* __restrict__ in, u16* __restrict__ out, int K, int N) {
  __shared__ float t[32][33];
  int n0 = blockIdx.x * 32, k0 = blockIdx.y * 32;
  int tx = threadIdx.x, ty = threadIdx.y;  // 32 x 8
#pragma unroll
  for (int i = ty; i < 32; i += 8) t[i][tx] = in[(size_t)(k0 + i) * N + n0 + tx];
  __syncthreads();
#pragma unroll
  for (int i = ty; i < 32; i += 8)
    out[(size_t)(n0 + i) * K + k0 + tx] = f2bf(t[tx][i]);
}

// ---------------- GEMM, 2-phase double-buffered ----------------
template <int TM, int OUTF32, int RELU>
__global__ __launch_bounds__(256) void gemm_bt(const u16* __restrict__ A,
                                               const u16* __restrict__ BT,
                                               const float* __restrict__ bias,
                                               float* __restrict__ Cf,
                                               u16* __restrict__ Cb,
                                               int M, int N, int K) {
  constexpr int MR = TM / 32;
  constexpr int ACH = TM / 64;
  __shared__ __align__(16) u16 lA[2][TM * 32];
  __shared__ __align__(16) u16 lB[2][128 * 32];
  const int tid = threadIdx.x;
  const int lane = tid & 63, wave = tid >> 6;
  const int bm = blockIdx.y * TM, bn = blockIdx.x * 128;
  const int wr = (wave >> 1) * (MR * 16), wc = (wave & 1) * 64;
  const int r16 = lane & 15, kg = lane >> 4;

  f32x4 acc[MR][4] = {};

  auto stage = [&](int buf, int k0) {
#pragma unroll
    for (int c = 0; c < ACH; ++c) {
      int chunk = c * 256 + tid;
      int r = chunk >> 2, kc = (chunk & 3) * 8;
      gl_lds16(&A[(size_t)(bm + r) * K + k0 + kc], &lA[buf][(c * 256 + wave * 64) * 8]);
    }
#pragma unroll
    for (int c = 0; c < 2; ++c) {
      int chunk = c * 256 + tid;
      int r = chunk >> 2, kc = (chunk & 3) * 8;
      gl_lds16(&BT[(size_t)(bn + r) * K + k0 + kc], &lB[buf][(c * 256 + wave * 64) * 8]);
    }
  };

  stage(0, 0);
  __syncthreads();

  const int nk = K / 32;
  for (int i = 0; i < nk; ++i) {
    const int cur = i & 1;
    if (i + 1 < nk) stage(cur ^ 1, (i + 1) * 32);

    bf16x8 af[MR], bfr[4];
#pragma unroll
    for (int m = 0; m < MR; ++m)
      af[m] = *reinterpret_cast<const bf16x8*>(&lA[cur][(wr + m * 16 + r16) * 32 + kg * 8]);
#pragma unroll
    for (int n = 0; n < 4; ++n)
      bfr[n] = *reinterpret_cast<const bf16x8*>(&lB[cur][(wc + n * 16 + r16) * 32 + kg * 8]);
#pragma unroll
    for (int m = 0; m < MR; ++m)
#pragma unroll
      for (int n = 0; n < 4; ++n)
        acc[m][n] = __builtin_amdgcn_mfma_f32_16x16x32_bf16(af[m], bfr[n], acc[m][n], 0, 0, 0);

    __syncthreads();
  }

#pragma unroll
  for (int m = 0; m < MR; ++m) {
    int row = bm + wr + m * 16 + kg * 4;
#pragma unroll
    for (int n = 0; n < 4; ++n) {
      int col = bn + wc + n * 16 + r16;
      float bv = bias[col];
#pragma unroll
      for (int j = 0; j < 4; ++j) {
        float v = acc[m][n][j] + bv;
        if (RELU) v = fmaxf(v, 0.f);
        if (OUTF32)
          Cf[(size_t)(row + j) * N + col] = v;
        else
          Cb[(size_t)(row + j) * N + col] = f2bf(v);
      }
    }
  }
}

// ---------------- V transpose via LDS: 64x64 tiles ----------------
__global__ __launch_bounds__(256) void vt_kern(const u16* __restrict__ src, int stride,
                                               int hmul, int hadd, u16* __restrict__ VT) {
  __shared__ u16 lt[64][72];
  const int bh = blockIdx.y;
  const int b = bh >> 4, h = bh & 15;
  const int s0 = blockIdx.x * 64;
  const u16* sb = src + (size_t)b * NS * stride + h * hmul + hadd;
#pragma unroll
  for (int c = 0; c < 2; ++c) {
    int chunk = c * 256 + threadIdx.x;
    int r = chunk >> 3, d = (chunk & 7) * 8;
    *reinterpret_cast<uint4*>(&lt[r][d]) =
        *reinterpret_cast<const uint4*>(&sb[(size_t)(s0 + r) * stride + d]);
  }
  __syncthreads();
  const int d = threadIdx.x >> 2, sq = (threadIdx.x & 3) * 16;
  union { u16 e[16]; uint4 v[2]; } pk;
#pragma unroll
  for (int i = 0; i < 16; ++i) pk.e[i] = lt[sq + i][d];
  uint4* dst = reinterpret_cast<uint4*>(&VT[((size_t)bh * NHD + d) * NS + s0 + sq]);
  dst[0] = pk.v[0];
  dst[1] = pk.v[1];
}

// ---------------- flash attention v8: LDS-staged K/V with XOR swizzle ----------------
// grid (512, 2). Same structure as v7 but pitch-64 XOR-swizzled LDS:
// conflict-free fragment reads + 48KB LDS -> 3 blocks/CU (3 waves/SIMD).
#define C1F 0.180336880f  // 0.125 * log2(e)
#define OPSZ ((size_t)32 * NS * NHD)

template <int CAUSAL>
__global__ __launch_bounds__(256) void attn8(const u16* __restrict__ Qp, int qstride,
                                             int qhm, const u16* __restrict__ Kp,
                                             int kstride, int khm, int kha,
                                             const u16* __restrict__ VT,
                                             u16* __restrict__ OP,
                                             float2* __restrict__ ML) {
  const int bid = blockIdx.x;              // 512
  const int split = blockIdx.y;            // 0/1
  const int xcd = bid & 7, j5 = bid >> 3;
  const int bh = xcd + 8 * (j5 >> 4);      // 4 bh per XCD
  int qt = j5 & 15;
  if (CAUSAL) qt = 15 - qt;                // heavy q-tiles first
  const int b = bh >> 4, h = bh & 15;
  const int tid = threadIdx.x, lane = tid & 63, wave = tid >> 6;
  const int r16 = lane & 15, kg = lane >> 4;
  const int q0w = qt * 128 + wave * 32;

  __shared__ __align__(16) char lK[2][64 * 128];  // 16 KB (swizzled)
  __shared__ __align__(16) char lV[2][64 * 128];  // 16 KB (swizzled V^T)
  __shared__ __align__(16) char lP[4][32 * 128];  // 16 KB wave-private P
  char* lPw = &lP[wave][0];

  const u16* qb = Qp + (size_t)b * NS * qstride + h * qhm;
  const u16* kb = Kp + (size_t)b * NS * kstride + h * khm + kha;
  const u16* vb = VT + (size_t)bh * NHD * NS;

  // staging split: thread covers rows (tid>>3) and (tid>>3)+32, 16B col chunk
  const int srow = tid >> 3;
  const int sbcol = (tid & 7) * 16;   // byte column
  const int scol = (tid & 7) * 8;     // element column

  bf16x8 qf[2][2];
#pragma unroll
  for (int qn = 0; qn < 2; ++qn)
#pragma unroll
    for (int ks = 0; ks < 2; ++ks)
      qf[qn][ks] = *reinterpret_cast<const bf16x8*>(
          &qb[(size_t)(q0w + qn * 16 + r16) * qstride + ks * 32 + kg * 8]);

  f32x4 o_acc[2][4] = {};
  float m_run[2] = {-1e30f, -1e30f}, l_lane[2] = {0.f, 0.f};

  // block-uniform tile range; wave-level compute bound
  const int ntb = CAUSAL ? (2 * qt + 2) : (NS / 64);        // block tiles
  const int wnt = CAUSAL ? (q0w / 64 + 1) : (NS / 64);      // wave tiles
  const int halfb = (ntb + 1) >> 1;
  const int t0 = split ? halfb : 0;
  const int t1 = split ? ntb : halfb;

  uint4 kreg[2], vreg[2];
  auto ldregs = [&](int t) {
    const int kv0 = t * 64;
#pragma unroll
    for (int c = 0; c < 2; ++c) {
      kreg[c] = *reinterpret_cast<const uint4*>(
          &kb[(size_t)(kv0 + srow + c * 32) * kstride + scol]);
      vreg[c] = *reinterpret_cast<const uint4*>(
          &vb[(size_t)(srow + c * 32) * NS + kv0 + scol]);
    }
  };
  auto wrlds = [&](int buf) {
#pragma unroll
    for (int c = 0; c < 2; ++c) {
      *reinterpret_cast<uint4*>(lswz(lK[buf], srow + c * 32, sbcol)) = kreg[c];
      *reinterpret_cast<uint4*>(lswz(lV[buf], srow + c * 32, sbcol)) = vreg[c];
    }
  };

  ldregs(t0);
  wrlds(0);
  __syncthreads();

  for (int t = t0; t < t1; ++t) {
    const int cur = (t - t0) & 1;
    const bool more = (t + 1 < t1);
    if (more) ldregs(t + 1);   // global loads in flight during compute

    if (t < wnt) {
      const int kv0 = t * 64;
      const char* lKc = lK[cur];
      const char* lVc = lV[cur];

      bf16x8 kf[8];
#pragma unroll
      for (int c = 0; c < 4; ++c)
#pragma unroll
        for (int ks = 0; ks < 2; ++ks)
          kf[c * 2 + ks] = *reinterpret_cast<const bf16x8*>(
              lswz(lKc, c * 16 + r16, ks * 64 + kg * 16));

      f32x4 s[2][4] = {};
#pragma unroll
      for (int c = 0; c < 4; ++c)
#pragma unroll
        for (int ks = 0; ks < 2; ++ks) {
          s[0][c] = __builtin_amdgcn_mfma_f32_16x16x32_bf16(kf[c * 2 + ks], qf[0][ks], s[0][c], 0, 0, 0);
          s[1][c] = __builtin_amdgcn_mfma_f32_16x16x32_bf16(kf[c * 2 + ks], qf[1][ks], s[1][c], 0, 0, 0);
        }

      // V frag reads issued now: ds latency overlaps softmax VALU
      bf16x8 vf[8];
#pragma unroll
      for (int cd = 0; cd < 4; ++cd)
#pragma unroll
        for (int ks = 0; ks < 2; ++ks)
          vf[cd * 2 + ks] = *reinterpret_cast<const bf16x8*>(
              lswz(lVc, cd * 16 + r16, ks * 64 + kg * 16));

#pragma unroll
      for (int qn = 0; qn < 2; ++qn) {
        if (CAUSAL && t == wnt - 1) {
          const int q = q0w + qn * 16 + r16;
#pragma unroll
          for (int c = 0; c < 4; ++c)
#pragma unroll
            for (int j = 0; j < 4; ++j)
              if (kv0 + c * 16 + kg * 4 + j > q) s[qn][c][j] = -1e31f;
        }
        float mxr = s[qn][0][0];
#pragma unroll
        for (int c = 0; c < 4; ++c)
#pragma unroll
          for (int j = 0; j < 4; ++j) mxr = fmaxf(mxr, s[qn][c][j]);
        float mn = m_run[qn];
        if (!__all(mxr * C1F <= mn + 8.f)) {   // rescale: rare (defer-max T13)
          float mz = mxr * C1F;
          mz = fmaxf(mz, __shfl_xor(mz, 16));
          mz = fmaxf(mz, __shfl_xor(mz, 32));
          mn = fmaxf(m_run[qn], mz);
          const float cr = exp2f(m_run[qn] - mn);
          m_run[qn] = mn;
          l_lane[qn] *= cr;
          float crow[4];
#pragma unroll
          for (int j = 0; j < 4; ++j) crow[j] = __shfl(cr, kg * 4 + j);
#pragma unroll
          for (int cd = 0; cd < 4; ++cd)
#pragma unroll
            for (int j = 0; j < 4; ++j) o_acc[qn][cd][j] *= crow[j];
        }
        float su = 0.f;
#pragma unroll
        for (int c = 0; c < 4; ++c)
#pragma unroll
          for (int j = 0; j < 4; ++j) {
            float p = exp2f(fmaf(s[qn][c][j], C1F, -mn));
            s[qn][c][j] = p;
            su += p;
          }
        l_lane[qn] += su;

#pragma unroll
        for (int c = 0; c < 4; ++c) {
          uint2 w2 = {pkbf(s[qn][c][0], s[qn][c][1]), pkbf(s[qn][c][2], s[qn][c][3])};
          *reinterpret_cast<uint2*>(lswz(lPw, qn * 16 + r16, c * 32 + kg * 8)) = w2;
        }
      }

      bf16x8 pf[2][2];
#pragma unroll
      for (int qn = 0; qn < 2; ++qn)
#pragma unroll
        for (int ks = 0; ks < 2; ++ks)
          pf[qn][ks] = *reinterpret_cast<const bf16x8*>(
              lswz(lPw, qn * 16 + r16, ks * 64 + kg * 16));
#pragma unroll
      for (int cd = 0; cd < 4; ++cd)
#pragma unroll
        for (int ks = 0; ks < 2; ++ks) {
          o_acc[0][cd] = __builtin_amdgcn_mfma_f32_16x16x32_bf16(pf[0][ks], vf[cd * 2 + ks],
                                                                 o_acc[0][cd], 0, 0, 0);
          o_acc[1][cd] = __builtin_amdgcn_mfma_f32_16x16x32_bf16(pf[1][ks], vf[cd * 2 + ks],
                                                                 o_acc[1][cd], 0, 0, 0);
        }
    }

    if (more) wrlds(cur ^ 1);  // waits vmcnt via register dependency
    __syncthreads();           // one barrier per tile
  }

  // epilogue: un-normalized partials + (m, l)
  u16* op = OP + split * OPSZ + (size_t)bh * NS * NHD;
#pragma unroll
  for (int qn = 0; qn < 2; ++qn) {
    float l = l_lane[qn];
    l += __shfl_xor(l, 16);
    l += __shfl_xor(l, 32);
#pragma unroll
    for (int cd = 0; cd < 4; ++cd) {
      int col = cd * 16 + r16;
#pragma unroll
      for (int j = 0; j < 4; ++j) {
        int row = q0w + qn * 16 + kg * 4 + j;
        op[(size_t)row * NHD + col] = f2bf(o_acc[qn][cd][j]);
      }
    }
    if (kg == 0)
      ML[(size_t)split * 32 * NS + (size_t)bh * NS + q0w + qn * 16 + r16] =
          make_float2(m_run[qn], l);
  }
}

// ---------------- combine the two KV-splits ----------------
__global__ __launch_bounds__(256) void attn_comb(const u16* __restrict__ OP,
                                                 const float2* __restrict__ ML,
                                                 u16* __restrict__ AO) {
  int idx = blockIdx.x * 256 + threadIdx.x;   // 524288
  int dg = (idx & 7) * 8;
  int q = (idx >> 3) & (NS - 1);
  int bh = idx >> 14;
  int b = bh >> 4, h = bh & 15;
  float2 ml0 = ML[(size_t)bh * NS + q];
  float2 ml1 = ML[(size_t)32 * NS + (size_t)bh * NS + q];
  float M = fmaxf(ml0.x, ml1.x);
  float w0 = exp2f(ml0.x - M), w1 = exp2f(ml1.x - M);
  float linv = 1.f / (ml0.y * w0 + ml1.y * w1);
  w0 *= linv;
  w1 *= linv;
  size_t src = ((size_t)bh * NS + q) * NHD + dg;
  uint4 r0 = *reinterpret_cast<const uint4*>(&OP[src]);
  uint4 r1 = *reinterpret_cast<const uint4*>(&OP[OPSZ + src]);
  const u16* e0 = reinterpret_cast<const u16*>(&r0);
  const u16* e1 = reinterpret_cast<const u16*>(&r1);
  u16 out[8];
#pragma unroll
  for (int j = 0; j < 8; ++j)
    out[j] = f2bf(bf2f(e0[j]) * w0 + bf2f(e1[j]) * w1);
  *reinterpret_cast<uint4*>(&AO[((size_t)b * NS + q) * ND + h * NHD + dg]) =
      *reinterpret_cast<uint4*>(out);
}

// ---------------- fused residual + LayerNorm ----------------
__global__ __launch_bounds__(256) void ln_kern(const float* __restrict__ a,
                                               const float* __restrict__ resid,
                                               const float* __restrict__ g,
                                               const float* __restrict__ bb,
                                               float* __restrict__ outf,
                                               u16* __restrict__ outb) {
  const int row = blockIdx.x;
  const int tid = threadIdx.x;
  const size_t off = (size_t)row * ND + tid * 4;
  f32x4 v = *reinterpret_cast<const f32x4*>(&a[off]);
  f32x4 r = *reinterpret_cast<const f32x4*>(&resid[off]);
#pragma unroll
  for (int j = 0; j < 4; ++j) v[j] += r[j];
  float s = v[0] + v[1] + v[2] + v[3];
  float s2 = v[0] * v[0] + v[1] * v[1] + v[2] * v[2] + v[3] * v[3];
#pragma unroll
  for (int m = 1; m < 64; m <<= 1) {
    s += __shfl_xor(s, m);
    s2 += __shfl_xor(s2, m);
  }
  __shared__ float ws1[4], ws2[4];
  int wave = tid >> 6, lane = tid & 63;
  if (lane == 0) { ws1[wave] = s; ws2[wave] = s2; }
  __syncthreads();
  s = ws1[0] + ws1[1] + ws1[2] + ws1[3];
  s2 = ws2[0] + ws2[1] + ws2[2] + ws2[3];
  float mean = s * (1.f / ND);
  float var = fmaxf(s2 * (1.f / ND) - mean * mean, 0.f);
  float rstd = rsqrtf(var + 1e-9f);
  f32x4 gg = *reinterpret_cast<const f32x4*>(&g[tid * 4]);
  f32x4 bv = *reinterpret_cast<const f32x4*>(&bb[tid * 4]);
  f32x4 o;
  u16x4 ob;
#pragma unroll
  for (int j = 0; j < 4; ++j) {
    o[j] = gg[j] * (v[j] - mean) * rstd + bv[j];
    ob[j] = f2bf(o[j]);
  }
  *reinterpret_cast<f32x4*>(&outf[off]) = o;
  *reinterpret_cast<u16x4*>(&outb[off]) = ob;
}

// ---------------- host launch ----------------
extern "C" void kernel_launch(void* const* d_in, const int* in_sizes, int n_in,
                              void* d_out, int out_size, void* d_ws, size_t ws_size,
                              hipStream_t stream) {
  const float* x = (const float*)d_in[0];
  const float* y = (const float*)d_in[1];
  const float* qkv_w = (const float*)d_in[3];
  const float* qkv_b = (const float*)d_in[4];
  const float* sa_fc_w = (const float*)d_in[5];
  const float* sa_fc_b = (const float*)d_in[6];
  const float* g1 = (const float*)d_in[7];
  const float* b1 = (const float*)d_in[8];
  const float* kv_w = (const float*)d_in[9];
  const float* kv_b = (const float*)d_in[10];
  const float* q_w = (const float*)d_in[11];
  const float* q_b = (const float*)d_in[12];
  const float* ca_fc_w = (const float*)d_in[13];
  const float* ca_fc_b = (const float*)d_in[14];
  const float* g2 = (const float*)d_in[15];
  const float* b2 = (const float*)d_in[16];
  const float* ff1_w = (const float*)d_in[17];
  const float* ff1_b = (const float*)d_in[18];
  const float* ff2_w = (const float*)d_in[19];
  const float* ff2_b = (const float*)d_in[20];
  const float* g3 = (const float*)d_in[21];
  const float* b3 = (const float*)d_in[22];

  if (ws_size < (120ull << 20)) return;

  char* w = (char*)d_ws;
  u16* W16 = (u16*)(w + 0);              // 8 MB weights (ML aliases during attn)
  u16* ACT = (u16*)(w + (8ull << 20));   // 8 MB activation (OP split 0 aliases)
  u16* XB  = (u16*)(w + (16ull << 20));  // 8 MB x bf16 (OP split 1 aliases)
  u16* Qb  = (u16*)(w + (24ull << 20));  // 8 MB cross-attn Q
  u16* VT  = (u16*)(w + (40ull << 20));  // 8 MB V^T [bh][64][S]
  u16* AO  = (u16*)(w + (48ull << 20));  // 8 MB attention out
  u16* G   = (u16*)(w + (56ull << 20));  // 24 MB big GEMM out
  float* Fa = (float*)(w + (88ull << 20));   // 16 MB
  float* Fb = (float*)(w + (104ull << 20));  // 16 MB
  u16* OPb = ACT;
  float2* ML = (float2*)w;
  float* OUT = (float*)d_out;

  dim3 wblk(32, 8);
  const int n4act = NBS * ND / 4;

  // ---- self attention block ----
  conv_bf16<<<n4act / 256, 256, 0, stream>>>(y, ACT, n4act);
  wconv_t<<<dim3(3 * ND / 32, ND / 32), wblk, 0, stream>>>(qkv_w, W16, ND, 3 * ND);
  gemm_bt<128, 0, 0><<<dim3(3 * ND / 128, NBS / 128), 256, 0, stream>>>(
      ACT, W16, qkv_b, nullptr, G, NBS, 3 * ND, ND);
  vt_kern<<<dim3(NS / 64, NB * NH), 256, 0, stream>>>(G, 3 * ND, 192, 128, VT);
  attn8<1><<<dim3(512, 2), 256, 0, stream>>>(G, 3 * ND, 192, G, 3 * ND, 192, 64, VT, OPb, ML);
  attn_comb<<<2048, 256, 0, stream>>>(OPb, ML, AO);
  wconv_t<<<dim3(ND / 32, ND / 32), wblk, 0, stream>>>(sa_fc_w, W16, ND, ND);
  gemm_bt<64, 1, 0><<<dim3(ND / 128, NBS / 64), 256, 0, stream>>>(
      AO, W16, sa_fc_b, Fa, nullptr, NBS, ND, ND);
  ln_kern<<<NBS, 256, 0, stream>>>(Fa, y, g1, b1, Fb, ACT);  // y1

  // ---- cross attention block ----
  conv_bf16<<<n4act / 256, 256, 0, stream>>>(x, XB, n4act);
  wconv_t<<<dim3(2 * ND / 32, ND / 32), wblk, 0, stream>>>(kv_w, W16, ND, 2 * ND);
  gemm_bt<128, 0, 0><<<dim3(2 * ND / 128, NBS / 128), 256, 0, stream>>>(
      XB, W16, kv_b, nullptr, G, NBS, 2 * ND, ND);
  vt_kern<<<dim3(NS / 64, NB * NH), 256, 0, stream>>>(G, 2 * ND, 128, 64, VT);
  wconv_t<<<dim3(ND / 32, ND / 32), wblk, 0, stream>>>(q_w, W16, ND, ND);
  gemm_bt<64, 0, 0><<<dim3(ND / 128, NBS / 64), 256, 0, stream>>>(
      ACT, W16, q_b, nullptr, Qb, NBS, ND, ND);
  attn8<0><<<dim3(512, 2), 256, 0, stream>>>(Qb, ND, 64, G, 2 * ND, 128, 0, VT, OPb, ML);
  attn_comb<<<2048, 256, 0, stream>>>(OPb, ML, AO);
  wconv_t<<<dim3(ND / 32, ND / 32), wblk, 0, stream>>>(ca_fc_w, W16, ND, ND);
  gemm_bt<64, 1, 0><<<dim3(ND / 128, NBS / 64), 256, 0, stream>>>(
      AO, W16, ca_fc_b, Fa, nullptr, NBS, ND, ND);
  ln_kern<<<NBS, 256, 0, stream>>>(Fa, Fb, g2, b2, Fb, ACT);  // y2

  // ---- FFN ----
  wconv_t<<<dim3(NFF / 32, ND / 32), wblk, 0, stream>>>(ff1_w, W16, ND, NFF);
  gemm_bt<128, 0, 1><<<dim3(NFF / 128, NBS / 128), 256, 0, stream>>>(
      ACT, W16, ff1_b, nullptr, G, NBS, NFF, ND);
  wconv_t<<<dim3(ND / 32, NFF / 32), wblk, 0, stream>>>(ff2_w, W16, NFF, ND);
  gemm_bt<64, 1, 0><<<dim3(ND / 128, NBS / 64), 256, 0, stream>>>(
      G, W16, ff2_b, Fa, nullptr, NBS, ND, NFF);
  ln_kern<<<NBS, 256, 0, stream>>>(Fa, Fb, g3, b3, OUT, ACT);
}

// Round 9
// 467.187 us; speedup vs baseline: 2.3475x; 1.1091x over previous
//
#include <hip/hip_runtime.h>

typedef unsigned short u16;
typedef unsigned int u32;
typedef __attribute__((ext_vector_type(4))) float f32x4;
typedef __attribute__((ext_vector_type(8))) __bf16 bf16x8;
typedef __attribute__((ext_vector_type(2))) __bf16 bf16x2;
typedef __attribute__((ext_vector_type(4))) u16 u16x4;

#define NB 2
#define NS 2048
#define ND 1024
#define NH 16
#define NHD 64
#define NFF 4096
#define NBS (NB * NS)   // 4096 rows

typedef const __attribute__((address_space(1))) unsigned int as1_u32;
typedef __attribute__((address_space(3))) unsigned int as3_u32;

__device__ __forceinline__ void gl_lds16(const u16* g, u16* l) {
  __builtin_amdgcn_global_load_lds((as1_u32*)g, (as3_u32*)l, 16, 0, 0);
}

__device__ __forceinline__ u16 f2bf(float f) {
  union { float f; unsigned u; } v; v.f = f;
  unsigned r = (v.u + 0x7FFFu + ((v.u >> 16) & 1u)) >> 16;  // RNE
  return (u16)r;
}

__device__ __forceinline__ float bf2f(u16 u) {
  union { u32 u; float f; } v; v.u = ((u32)u) << 16; return v.f;
}

__device__ __forceinline__ u32 pkbf(float a, float b) {
  bf16x2 v; v[0] = (__bf16)a; v[1] = (__bf16)b;
  union { bf16x2 v; u32 u; } c; c.v = v; return c.u;
}

// XOR-swizzled LDS addressing (pitch 128B): bank-conflict-free for row-strided
// b128 fragment reads; XOR flips only bit 4 so 8B/16B alignment is preserved.
__device__ __forceinline__ char* lswz(void* base, int row, int bcol) {
  return (char*)base + row * 128 + (bcol ^ ((row & 7) << 4));
}
__device__ __forceinline__ const char* lswz(const void* base, int row, int bcol) {
  return (const char*)base + row * 128 + (bcol ^ ((row & 7) << 4));
}

// ---------------- f32 -> bf16 (vectorized) ----------------
__global__ __launch_bounds__(256) void conv_bf16(const float* __restrict__ in,
                                                 u16* __restrict__ out, int n4) {
  int i = blockIdx.x * 256 + threadIdx.x;
  if (i >= n4) return;
  f32x4 v = *reinterpret_cast<const f32x4*>(&in[(size_t)i * 4]);
  u16x4 o;
#pragma unroll
  for (int j = 0; j < 4; ++j) o[j] = f2bf(v[j]);
  *reinterpret_cast<u16x4*>(&out[(size_t)i * 4]) = o;
}

// ---------------- weight convert + transpose: [K,N] f32 -> [N,K] bf16 ----------------
__global__ void wconv_t(const float* __restrict__ in, u16* __restrict__ out, int K, int N) {
  __shared__ float t[32][33];
  int n0 = blockIdx.x * 32, k0 = blockIdx.y * 32;
  int tx = threadIdx.x, ty = threadIdx.y;  // 32 x 8
#pragma unroll
  for (int i = ty; i < 32; i += 8) t[i][tx] = in[(size_t)(k0 + i) * N + n0 + tx];
  __syncthreads();
#pragma unroll
  for (int i = ty; i < 32; i += 8)
    out[(size_t)(n0 + i) * K + k0 + tx] = f2bf(t[tx][i]);
}

// ---------------- GEMM, 2-phase double-buffered ----------------
template <int TM, int OUTF32, int RELU>
__global__ __launch_bounds__(256) void gemm_bt(const u16* __restrict__ A,
                                               const u16* __restrict__ BT,
                                               const float* __restrict__ bias,
                                               float* __restrict__ Cf,
                                               u16* __restrict__ Cb,
                                               int M, int N, int K) {
  constexpr int MR = TM / 32;
  constexpr int ACH = TM / 64;
  __shared__ __align__(16) u16 lA[2][TM * 32];
  __shared__ __align__(16) u16 lB[2][128 * 32];
  const int tid = threadIdx.x;
  const int lane = tid & 63, wave = tid >> 6;
  const int bm = blockIdx.y * TM, bn = blockIdx.x * 128;
  const int wr = (wave >> 1) * (MR * 16), wc = (wave & 1) * 64;
  const int r16 = lane & 15, kg = lane >> 4;

  f32x4 acc[MR][4] = {};

  auto stage = [&](int buf, int k0) {
#pragma unroll
    for (int c = 0; c < ACH; ++c) {
      int chunk = c * 256 + tid;
      int r = chunk >> 2, kc = (chunk & 3) * 8;
      gl_lds16(&A[(size_t)(bm + r) * K + k0 + kc], &lA[buf][(c * 256 + wave * 64) * 8]);
    }
#pragma unroll
    for (int c = 0; c < 2; ++c) {
      int chunk = c * 256 + tid;
      int r = chunk >> 2, kc = (chunk & 3) * 8;
      gl_lds16(&BT[(size_t)(bn + r) * K + k0 + kc], &lB[buf][(c * 256 + wave * 64) * 8]);
    }
  };

  stage(0, 0);
  __syncthreads();

  const int nk = K / 32;
  for (int i = 0; i < nk; ++i) {
    const int cur = i & 1;
    if (i + 1 < nk) stage(cur ^ 1, (i + 1) * 32);

    bf16x8 af[MR], bfr[4];
#pragma unroll
    for (int m = 0; m < MR; ++m)
      af[m] = *reinterpret_cast<const bf16x8*>(&lA[cur][(wr + m * 16 + r16) * 32 + kg * 8]);
#pragma unroll
    for (int n = 0; n < 4; ++n)
      bfr[n] = *reinterpret_cast<const bf16x8*>(&lB[cur][(wc + n * 16 + r16) * 32 + kg * 8]);
#pragma unroll
    for (int m = 0; m < MR; ++m)
#pragma unroll
      for (int n = 0; n < 4; ++n)
        acc[m][n] = __builtin_amdgcn_mfma_f32_16x16x32_bf16(af[m], bfr[n], acc[m][n], 0, 0, 0);

    __syncthreads();
  }

#pragma unroll
  for (int m = 0; m < MR; ++m) {
    int row = bm + wr + m * 16 + kg * 4;
#pragma unroll
    for (int n = 0; n < 4; ++n) {
      int col = bn + wc + n * 16 + r16;
      float bv = bias[col];
#pragma unroll
      for (int j = 0; j < 4; ++j) {
        float v = acc[m][n][j] + bv;
        if (RELU) v = fmaxf(v, 0.f);
        if (OUTF32)
          Cf[(size_t)(row + j) * N + col] = v;
        else
          Cb[(size_t)(row + j) * N + col] = f2bf(v);
      }
    }
  }
}

// ---------------- V transpose via LDS: 64x64 tiles ----------------
__global__ __launch_bounds__(256) void vt_kern(const u16* __restrict__ src, int stride,
                                               int hmul, int hadd, u16* __restrict__ VT) {
  __shared__ u16 lt[64][72];
  const int bh = blockIdx.y;
  const int b = bh >> 4, h = bh & 15;
  const int s0 = blockIdx.x * 64;
  const u16* sb = src + (size_t)b * NS * stride + h * hmul + hadd;
#pragma unroll
  for (int c = 0; c < 2; ++c) {
    int chunk = c * 256 + threadIdx.x;
    int r = chunk >> 3, d = (chunk & 7) * 8;
    *reinterpret_cast<uint4*>(&lt[r][d]) =
        *reinterpret_cast<const uint4*>(&sb[(size_t)(s0 + r) * stride + d]);
  }
  __syncthreads();
  const int d = threadIdx.x >> 2, sq = (threadIdx.x & 3) * 16;
  union { u16 e[16]; uint4 v[2]; } pk;
#pragma unroll
  for (int i = 0; i < 16; ++i) pk.e[i] = lt[sq + i][d];
  uint4* dst = reinterpret_cast<uint4*>(&VT[((size_t)bh * NHD + d) * NS + s0 + sq]);
  dst[0] = pk.v[0];
  dst[1] = pk.v[1];
}

// ---------------- flash attention v9: 8-wave blocks, pre-scaled Q ----------------
// grid (256, 2), 512 threads. One K/V staging serves 8 waves (2x amortization vs v8);
// LDS 64KB -> 2 blocks/CU = 16 waves/CU. Q pre-scaled by 0.125*log2e at prologue
// so the inner loop exp path is sub+exp2 only.
#define C1F 0.180336880f  // 0.125 * log2(e)
#define OPSZ ((size_t)32 * NS * NHD)

template <int CAUSAL>
__global__ __launch_bounds__(512) void attn9(const u16* __restrict__ Qp, int qstride,
                                             int qhm, const u16* __restrict__ Kp,
                                             int kstride, int khm, int kha,
                                             const u16* __restrict__ VT,
                                             u16* __restrict__ OP,
                                             float2* __restrict__ ML) {
  const int bid = blockIdx.x;              // 256
  const int split = blockIdx.y;            // 0/1
  const int xcd = bid & 7, j5 = bid >> 3;  // j5: 0..31
  const int bh = xcd + 8 * (j5 >> 3);      // 4 bh per XCD
  int qt = j5 & 7;
  if (CAUSAL) qt = 7 - qt;                 // heavy q-tiles first
  const int b = bh >> 4, h = bh & 15;
  const int tid = threadIdx.x, lane = tid & 63, wave = tid >> 6;  // 8 waves
  const int r16 = lane & 15, kg = lane >> 4;
  const int q0w = qt * 256 + wave * 32;

  __shared__ __align__(16) char lK[2][64 * 128];  // 16 KB (swizzled)
  __shared__ __align__(16) char lV[2][64 * 128];  // 16 KB (swizzled V^T)
  __shared__ __align__(16) char lP[8][32 * 128];  // 32 KB wave-private P
  char* lPw = &lP[wave][0];

  const u16* qb = Qp + (size_t)b * NS * qstride + h * qhm;
  const u16* kb = Kp + (size_t)b * NS * kstride + h * khm + kha;
  const u16* vb = VT + (size_t)bh * NHD * NS;

  // staging: 512 threads cover 64 rows x 128B (1 x 16B load each for K and V)
  const int srow = tid >> 3;
  const int sbcol = (tid & 7) * 16;   // byte column
  const int scol = (tid & 7) * 8;     // element column

  // Q fragments, pre-scaled by C1F (moves the softmax scale out of the loop)
  bf16x8 qf[2][2];
#pragma unroll
  for (int qn = 0; qn < 2; ++qn)
#pragma unroll
    for (int ks = 0; ks < 2; ++ks) {
      bf16x8 v = *reinterpret_cast<const bf16x8*>(
          &qb[(size_t)(q0w + qn * 16 + r16) * qstride + ks * 32 + kg * 8]);
#pragma unroll
      for (int e = 0; e < 8; ++e) v[e] = (__bf16)((float)v[e] * C1F);
      qf[qn][ks] = v;
    }

  f32x4 o_acc[2][4] = {};
  float m_run[2] = {-1e30f, -1e30f}, l_lane[2] = {0.f, 0.f};

  // block-uniform tile range; wave-level compute bound
  const int ntb = CAUSAL ? (4 * qt + 4) : (NS / 64);        // block tiles
  const int wnt = CAUSAL ? (q0w / 64 + 1) : (NS / 64);      // wave tiles
  const int halfb = (ntb + 1) >> 1;
  const int t0 = split ? halfb : 0;
  const int t1 = split ? ntb : halfb;

  uint4 kreg, vreg;
  auto ldregs = [&](int t) {
    const int kv0 = t * 64;
    kreg = *reinterpret_cast<const uint4*>(&kb[(size_t)(kv0 + srow) * kstride + scol]);
    vreg = *reinterpret_cast<const uint4*>(&vb[(size_t)srow * NS + kv0 + scol]);
  };
  auto wrlds = [&](int buf) {
    *reinterpret_cast<uint4*>(lswz(lK[buf], srow, sbcol)) = kreg;
    *reinterpret_cast<uint4*>(lswz(lV[buf], srow, sbcol)) = vreg;
  };

  ldregs(t0);
  wrlds(0);
  __syncthreads();

  for (int t = t0; t < t1; ++t) {
    const int cur = (t - t0) & 1;
    const bool more = (t + 1 < t1);
    if (more) ldregs(t + 1);   // global loads in flight during compute

    if (t < wnt) {
      const int kv0 = t * 64;
      const char* lKc = lK[cur];
      const char* lVc = lV[cur];

      bf16x8 kf[8];
#pragma unroll
      for (int c = 0; c < 4; ++c)
#pragma unroll
        for (int ks = 0; ks < 2; ++ks)
          kf[c * 2 + ks] = *reinterpret_cast<const bf16x8*>(
              lswz(lKc, c * 16 + r16, ks * 64 + kg * 16));

      f32x4 s[2][4] = {};
#pragma unroll
      for (int c = 0; c < 4; ++c)
#pragma unroll
        for (int ks = 0; ks < 2; ++ks) {
          s[0][c] = __builtin_amdgcn_mfma_f32_16x16x32_bf16(kf[c * 2 + ks], qf[0][ks], s[0][c], 0, 0, 0);
          s[1][c] = __builtin_amdgcn_mfma_f32_16x16x32_bf16(kf[c * 2 + ks], qf[1][ks], s[1][c], 0, 0, 0);
        }

      // V frag reads issued now: ds latency overlaps softmax VALU
      bf16x8 vf[8];
#pragma unroll
      for (int cd = 0; cd < 4; ++cd)
#pragma unroll
        for (int ks = 0; ks < 2; ++ks)
          vf[cd * 2 + ks] = *reinterpret_cast<const bf16x8*>(
              lswz(lVc, cd * 16 + r16, ks * 64 + kg * 16));

#pragma unroll
      for (int qn = 0; qn < 2; ++qn) {
        if (CAUSAL && t == wnt - 1) {
          const int q = q0w + qn * 16 + r16;
#pragma unroll
          for (int c = 0; c < 4; ++c)
#pragma unroll
            for (int j = 0; j < 4; ++j)
              if (kv0 + c * 16 + kg * 4 + j > q) s[qn][c][j] = -1e31f;
        }
        // lane-local max (log2 domain already); max3-friendly chains
        float m0 = fmaxf(fmaxf(s[qn][0][0], s[qn][0][1]), fmaxf(s[qn][0][2], s[qn][0][3]));
        float m1 = fmaxf(fmaxf(s[qn][1][0], s[qn][1][1]), fmaxf(s[qn][1][2], s[qn][1][3]));
        float m2 = fmaxf(fmaxf(s[qn][2][0], s[qn][2][1]), fmaxf(s[qn][2][2], s[qn][2][3]));
        float m3 = fmaxf(fmaxf(s[qn][3][0], s[qn][3][1]), fmaxf(s[qn][3][2], s[qn][3][3]));
        float mxr = fmaxf(fmaxf(m0, m1), fmaxf(m2, m3));
        float mn = m_run[qn];
        if (!__all(mxr <= mn + 8.f)) {   // rescale: rare (defer-max T13)
          float mz = mxr;
          mz = fmaxf(mz, __shfl_xor(mz, 16));
          mz = fmaxf(mz, __shfl_xor(mz, 32));
          mn = fmaxf(m_run[qn], mz);
          const float cr = exp2f(m_run[qn] - mn);
          m_run[qn] = mn;
          l_lane[qn] *= cr;
          float crow[4];
#pragma unroll
          for (int j = 0; j < 4; ++j) crow[j] = __shfl(cr, kg * 4 + j);
#pragma unroll
          for (int cd = 0; cd < 4; ++cd)
#pragma unroll
            for (int j = 0; j < 4; ++j) o_acc[qn][cd][j] *= crow[j];
        }
        float su = 0.f;
#pragma unroll
        for (int c = 0; c < 4; ++c)
#pragma unroll
          for (int j = 0; j < 4; ++j) {
            float p = exp2f(s[qn][c][j] - mn);
            s[qn][c][j] = p;
            su += p;
          }
        l_lane[qn] += su;

#pragma unroll
        for (int c = 0; c < 4; ++c) {
          uint2 w2 = {pkbf(s[qn][c][0], s[qn][c][1]), pkbf(s[qn][c][2], s[qn][c][3])};
          *reinterpret_cast<uint2*>(lswz(lPw, qn * 16 + r16, c * 32 + kg * 8)) = w2;
        }
      }

      bf16x8 pf[2][2];
#pragma unroll
      for (int qn = 0; qn < 2; ++qn)
#pragma unroll
        for (int ks = 0; ks < 2; ++ks)
          pf[qn][ks] = *reinterpret_cast<const bf16x8*>(
              lswz(lPw, qn * 16 + r16, ks * 64 + kg * 16));
#pragma unroll
      for (int cd = 0; cd < 4; ++cd)
#pragma unroll
        for (int ks = 0; ks < 2; ++ks) {
          o_acc[0][cd] = __builtin_amdgcn_mfma_f32_16x16x32_bf16(pf[0][ks], vf[cd * 2 + ks],
                                                                 o_acc[0][cd], 0, 0, 0);
          o_acc[1][cd] = __builtin_amdgcn_mfma_f32_16x16x32_bf16(pf[1][ks], vf[cd * 2 + ks],
                                                                 o_acc[1][cd], 0, 0, 0);
        }
    }

    if (more) wrlds(cur ^ 1);  // waits vmcnt via register dependency
    __syncthreads();           // one barrier per tile
  }

  // epilogue: un-normalized partials + (m, l)
  u16* op = OP + split * OPSZ + (size_t)bh * NS * NHD;
#pragma unroll
  for (int qn = 0; qn < 2; ++qn) {
    float l = l_lane[qn];
    l += __shfl_xor(l, 16);
    l += __shfl_xor(l, 32);
#pragma unroll
    for (int cd = 0; cd < 4; ++cd) {
      int col = cd * 16 + r16;
#pragma unroll
      for (int j = 0; j < 4; ++j) {
        int row = q0w + qn * 16 + kg * 4 + j;
        op[(size_t)row * NHD + col] = f2bf(o_acc[qn][cd][j]);
      }
    }
    if (kg == 0)
      ML[(size_t)split * 32 * NS + (size_t)bh * NS + q0w + qn * 16 + r16] =
          make_float2(m_run[qn], l);
  }
}

// ---------------- combine the two KV-splits ----------------
__global__ __launch_bounds__(256) void attn_comb(const u16* __restrict__ OP,
                                                 const float2* __restrict__ ML,
                                                 u16* __restrict__ AO) {
  int idx = blockIdx.x * 256 + threadIdx.x;   // 524288
  int dg = (idx & 7) * 8;
  int q = (idx >> 3) & (NS - 1);
  int bh = idx >> 14;
  int b = bh >> 4, h = bh & 15;
  float2 ml0 = ML[(size_t)bh * NS + q];
  float2 ml1 = ML[(size_t)32 * NS + (size_t)bh * NS + q];
  float M = fmaxf(ml0.x, ml1.x);
  float w0 = exp2f(ml0.x - M), w1 = exp2f(ml1.x - M);
  float linv = 1.f / (ml0.y * w0 + ml1.y * w1);
  w0 *= linv;
  w1 *= linv;
  size_t src = ((size_t)bh * NS + q) * NHD + dg;
  uint4 r0 = *reinterpret_cast<const uint4*>(&OP[src]);
  uint4 r1 = *reinterpret_cast<const uint4*>(&OP[OPSZ + src]);
  const u16* e0 = reinterpret_cast<const u16*>(&r0);
  const u16* e1 = reinterpret_cast<const u16*>(&r1);
  u16 out[8];
#pragma unroll
  for (int j = 0; j < 8; ++j)
    out[j] = f2bf(bf2f(e0[j]) * w0 + bf2f(e1[j]) * w1);
  *reinterpret_cast<uint4*>(&AO[((size_t)b * NS + q) * ND + h * NHD + dg]) =
      *reinterpret_cast<uint4*>(out);
}

// ---------------- fused residual + LayerNorm ----------------
__global__ __launch_bounds__(256) void ln_kern(const float* __restrict__ a,
                                               const float* __restrict__ resid,
                                               const float* __restrict__ g,
                                               const float* __restrict__ bb,
                                               float* __restrict__ outf,
                                               u16* __restrict__ outb) {
  const int row = blockIdx.x;
  const int tid = threadIdx.x;
  const size_t off = (size_t)row * ND + tid * 4;
  f32x4 v = *reinterpret_cast<const f32x4*>(&a[off]);
  f32x4 r = *reinterpret_cast<const f32x4*>(&resid[off]);
#pragma unroll
  for (int j = 0; j < 4; ++j) v[j] += r[j];
  float s = v[0] + v[1] + v[2] + v[3];
  float s2 = v[0] * v[0] + v[1] * v[1] + v[2] * v[2] + v[3] * v[3];
#pragma unroll
  for (int m = 1; m < 64; m <<= 1) {
    s += __shfl_xor(s, m);
    s2 += __shfl_xor(s2, m);
  }
  __shared__ float ws1[4], ws2[4];
  int wave = tid >> 6, lane = tid & 63;
  if (lane == 0) { ws1[wave] = s; ws2[wave] = s2; }
  __syncthreads();
  s = ws1[0] + ws1[1] + ws1[2] + ws1[3];
  s2 = ws2[0] + ws2[1] + ws2[2] + ws2[3];
  float mean = s * (1.f / ND);
  float var = fmaxf(s2 * (1.f / ND) - mean * mean, 0.f);
  float rstd = rsqrtf(var + 1e-9f);
  f32x4 gg = *reinterpret_cast<const f32x4*>(&g[tid * 4]);
  f32x4 bv = *reinterpret_cast<const f32x4*>(&bb[tid * 4]);
  f32x4 o;
  u16x4 ob;
#pragma unroll
  for (int j = 0; j < 4; ++j) {
    o[j] = gg[j] * (v[j] - mean) * rstd + bv[j];
    ob[j] = f2bf(o[j]);
  }
  *reinterpret_cast<f32x4*>(&outf[off]) = o;
  *reinterpret_cast<u16x4*>(&outb[off]) = ob;
}

// ---------------- host launch ----------------
extern "C" void kernel_launch(void* const* d_in, const int* in_sizes, int n_in,
                              void* d_out, int out_size, void* d_ws, size_t ws_size,
                              hipStream_t stream) {
  const float* x = (const float*)d_in[0];
  const float* y = (const float*)d_in[1];
  const float* qkv_w = (const float*)d_in[3];
  const float* qkv_b = (const float*)d_in[4];
  const float* sa_fc_w = (const float*)d_in[5];
  const float* sa_fc_b = (const float*)d_in[6];
  const float* g1 = (const float*)d_in[7];
  const float* b1 = (const float*)d_in[8];
  const float* kv_w = (const float*)d_in[9];
  const float* kv_b = (const float*)d_in[10];
  const float* q_w = (const float*)d_in[11];
  const float* q_b = (const float*)d_in[12];
  const float* ca_fc_w = (const float*)d_in[13];
  const float* ca_fc_b = (const float*)d_in[14];
  const float* g2 = (const float*)d_in[15];
  const float* b2 = (const float*)d_in[16];
  const float* ff1_w = (const float*)d_in[17];
  const float* ff1_b = (const float*)d_in[18];
  const float* ff2_w = (const float*)d_in[19];
  const float* ff2_b = (const float*)d_in[20];
  const float* g3 = (const float*)d_in[21];
  const float* b3 = (const float*)d_in[22];

  if (ws_size < (120ull << 20)) return;

  char* w = (char*)d_ws;
  u16* W16 = (u16*)(w + 0);              // 8 MB weights (ML aliases during attn)
  u16* ACT = (u16*)(w + (8ull << 20));   // 8 MB activation (OP split 0 aliases)
  u16* XB  = (u16*)(w + (16ull << 20));  // 8 MB x bf16 (OP split 1 aliases)
  u16* Qb  = (u16*)(w + (24ull << 20));  // 8 MB cross-attn Q
  u16* VT  = (u16*)(w + (40ull << 20));  // 8 MB V^T [bh][64][S]
  u16* AO  = (u16*)(w + (48ull << 20));  // 8 MB attention out
  u16* G   = (u16*)(w + (56ull << 20));  // 24 MB big GEMM out
  float* Fa = (float*)(w + (88ull << 20));   // 16 MB
  float* Fb = (float*)(w + (104ull << 20));  // 16 MB
  u16* OPb = ACT;
  float2* ML = (float2*)w;
  float* OUT = (float*)d_out;

  dim3 wblk(32, 8);
  const int n4act = NBS * ND / 4;

  // ---- self attention block ----
  conv_bf16<<<n4act / 256, 256, 0, stream>>>(y, ACT, n4act);
  wconv_t<<<dim3(3 * ND / 32, ND / 32), wblk, 0, stream>>>(qkv_w, W16, ND, 3 * ND);
  gemm_bt<128, 0, 0><<<dim3(3 * ND / 128, NBS / 128), 256, 0, stream>>>(
      ACT, W16, qkv_b, nullptr, G, NBS, 3 * ND, ND);
  vt_kern<<<dim3(NS / 64, NB * NH), 256, 0, stream>>>(G, 3 * ND, 192, 128, VT);
  attn9<1><<<dim3(256, 2), 512, 0, stream>>>(G, 3 * ND, 192, G, 3 * ND, 192, 64, VT, OPb, ML);
  attn_comb<<<2048, 256, 0, stream>>>(OPb, ML, AO);
  wconv_t<<<dim3(ND / 32, ND / 32), wblk, 0, stream>>>(sa_fc_w, W16, ND, ND);
  gemm_bt<64, 1, 0><<<dim3(ND / 128, NBS / 64), 256, 0, stream>>>(
      AO, W16, sa_fc_b, Fa, nullptr, NBS, ND, ND);
  ln_kern<<<NBS, 256, 0, stream>>>(Fa, y, g1, b1, Fb, ACT);  // y1

  // ---- cross attention block ----
  conv_bf16<<<n4act / 256, 256, 0, stream>>>(x, XB, n4act);
  wconv_t<<<dim3(2 * ND / 32, ND / 32), wblk, 0, stream>>>(kv_w, W16, ND, 2 * ND);
  gemm_bt<128, 0, 0><<<dim3(2 * ND / 128, NBS / 128), 256, 0, stream>>>(
      XB, W16, kv_b, nullptr, G, NBS, 2 * ND, ND);
  vt_kern<<<dim3(NS / 64, NB * NH), 256, 0, stream>>>(G, 2 * ND, 128, 64, VT);
  wconv_t<<<dim3(ND / 32, ND / 32), wblk, 0, stream>>>(q_w, W16, ND, ND);
  gemm_bt<64, 0, 0><<<dim3(ND / 128, NBS / 64), 256, 0, stream>>>(
      ACT, W16, q_b, nullptr, Qb, NBS, ND, ND);
  attn9<0><<<dim3(256, 2), 512, 0, stream>>>(Qb, ND, 64, G, 2 * ND, 128, 0, VT, OPb, ML);
  attn_comb<<<2048, 256, 0, stream>>>(OPb, ML, AO);
  wconv_t<<<dim3(ND / 32, ND / 32), wblk, 0, stream>>>(ca_fc_w, W16, ND, ND);
  gemm_bt<64, 1, 0><<<dim3(ND / 128, NBS / 64), 256, 0, stream>>>(
      AO, W16, ca_fc_b, Fa, nullptr, NBS, ND, ND);
  ln_kern<<<NBS, 256, 0, stream>>>(Fa, Fb, g2, b2, Fb, ACT);  // y2

  // ---- FFN ----
  wconv_t<<<dim3(NFF / 32, ND / 32), wblk, 0, stream>>>(ff1_w, W16, ND, NFF);
  gemm_bt<128, 0, 1><<<dim3(NFF / 128, NBS / 128), 256, 0, stream>>>(
      ACT, W16, ff1_b, nullptr, G, NBS, NFF, ND);
  wconv_t<<<dim3(ND / 32, NFF / 32), wblk, 0, stream>>>(ff2_w, W16, NFF, ND);
  gemm_bt<64, 1, 0><<<dim3(ND / 128, NBS / 64), 256, 0, stream>>>(
      G, W16, ff2_b, Fa, nullptr, NBS, ND, NFF);
  ln_kern<<<NBS, 256, 0, stream>>>(Fa, Fb, g3, b3, OUT, ACT);
}

// Round 10
// 465.929 us; speedup vs baseline: 2.3538x; 1.0027x over previous
//
#include <hip/hip_runtime.h>

typedef unsigned short u16;
typedef unsigned int u32;
typedef __attribute__((ext_vector_type(4))) float f32x4;
typedef __attribute__((ext_vector_type(8))) __bf16 bf16x8;
typedef __attribute__((ext_vector_type(2))) __bf16 bf16x2;
typedef __attribute__((ext_vector_type(4))) u16 u16x4;

#define NB 2
#define NS 2048
#define ND 1024
#define NH 16
#define NHD 64
#define NFF 4096
#define NBS (NB * NS)   // 4096 rows

typedef const __attribute__((address_space(1))) unsigned int as1_u32;
typedef __attribute__((address_space(3))) unsigned int as3_u32;

__device__ __forceinline__ void gl_lds16(const u16* g, u16* l) {
  __builtin_amdgcn_global_load_lds((as1_u32*)g, (as3_u32*)l, 16, 0, 0);
}

__device__ __forceinline__ u16 f2bf(float f) {
  union { float f; unsigned u; } v; v.f = f;
  unsigned r = (v.u + 0x7FFFu + ((v.u >> 16) & 1u)) >> 16;  // RNE
  return (u16)r;
}

__device__ __forceinline__ float bf2f(u16 u) {
  union { u32 u; float f; } v; v.u = ((u32)u) << 16; return v.f;
}

__device__ __forceinline__ u32 pkbf(float a, float b) {
  bf16x2 v; v[0] = (__bf16)a; v[1] = (__bf16)b;
  union { bf16x2 v; u32 u; } c; c.v = v; return c.u;
}

// XOR-swizzled LDS addressing (pitch 128B): bank-conflict-free for row-strided
// b128 fragment reads; XOR flips only bit 4 so 8B/16B alignment is preserved.
__device__ __forceinline__ char* lswz(void* base, int row, int bcol) {
  return (char*)base + row * 128 + (bcol ^ ((row & 7) << 4));
}
__device__ __forceinline__ const char* lswz(const void* base, int row, int bcol) {
  return (const char*)base + row * 128 + (bcol ^ ((row & 7) << 4));
}

// ---------------- f32 -> bf16 (vectorized) ----------------
__global__ __launch_bounds__(256) void conv_bf16(const float* __restrict__ in,
                                                 u16* __restrict__ out, int n4) {
  int i = blockIdx.x * 256 + threadIdx.x;
  if (i >= n4) return;
  f32x4 v = *reinterpret_cast<const f32x4*>(&in[(size_t)i * 4]);
  u16x4 o;
#pragma unroll
  for (int j = 0; j < 4; ++j) o[j] = f2bf(v[j]);
  *reinterpret_cast<u16x4*>(&out[(size_t)i * 4]) = o;
}

// ---------------- ALL weight converts+transposes in ONE kernel ----------------
struct WSeg { const float* src; u16* dst; int N; int tile0; };
struct WAll { WSeg s[7]; };

__global__ void wconv_all(WAll wa) {
  __shared__ float t[32][33];
  int bid = blockIdx.x;
  int si = 0;
#pragma unroll
  for (int i = 1; i < 7; ++i) si += (bid >= wa.s[i].tile0) ? 1 : 0;
  const WSeg sg = wa.s[si];
  const int tt = bid - sg.tile0;
  const int tilesx = sg.N >> 5;
  const int n0 = (tt % tilesx) * 32, k0 = (tt / tilesx) * 32;
  const int K = (si == 6) ? NFF : ND;  // ff2 has K=4096, all others K=1024
  int tx = threadIdx.x, ty = threadIdx.y;  // 32 x 8
#pragma unroll
  for (int i = ty; i < 32; i += 8) t[i][tx] = sg.src[(size_t)(k0 + i) * sg.N + n0 + tx];
  __syncthreads();
#pragma unroll
  for (int i = ty; i < 32; i += 8)
    sg.dst[(size_t)(n0 + i) * K + k0 + tx] = f2bf(t[tx][i]);
}

// ---------------- GEMM, 2-phase double-buffered ----------------
template <int TM, int OUTF32, int RELU>
__global__ __launch_bounds__(256) void gemm_bt(const u16* __restrict__ A,
                                               const u16* __restrict__ BT,
                                               const float* __restrict__ bias,
                                               float* __restrict__ Cf,
                                               u16* __restrict__ Cb,
                                               int M, int N, int K) {
  constexpr int MR = TM / 32;
  constexpr int ACH = TM / 64;
  __shared__ __align__(16) u16 lA[2][TM * 32];
  __shared__ __align__(16) u16 lB[2][128 * 32];
  const int tid = threadIdx.x;
  const int lane = tid & 63, wave = tid >> 6;
  const int bm = blockIdx.y * TM, bn = blockIdx.x * 128;
  const int wr = (wave >> 1) * (MR * 16), wc = (wave & 1) * 64;
  const int r16 = lane & 15, kg = lane >> 4;

  f32x4 acc[MR][4] = {};

  auto stage = [&](int buf, int k0) {
#pragma unroll
    for (int c = 0; c < ACH; ++c) {
      int chunk = c * 256 + tid;
      int r = chunk >> 2, kc = (chunk & 3) * 8;
      gl_lds16(&A[(size_t)(bm + r) * K + k0 + kc], &lA[buf][(c * 256 + wave * 64) * 8]);
    }
#pragma unroll
    for (int c = 0; c < 2; ++c) {
      int chunk = c * 256 + tid;
      int r = chunk >> 2, kc = (chunk & 3) * 8;
      gl_lds16(&BT[(size_t)(bn + r) * K + k0 + kc], &lB[buf][(c * 256 + wave * 64) * 8]);
    }
  };

  stage(0, 0);
  __syncthreads();

  const int nk = K / 32;
  for (int i = 0; i < nk; ++i) {
    const int cur = i & 1;
    if (i + 1 < nk) stage(cur ^ 1, (i + 1) * 32);

    bf16x8 af[MR], bfr[4];
#pragma unroll
    for (int m = 0; m < MR; ++m)
      af[m] = *reinterpret_cast<const bf16x8*>(&lA[cur][(wr + m * 16 + r16) * 32 + kg * 8]);
#pragma unroll
    for (int n = 0; n < 4; ++n)
      bfr[n] = *reinterpret_cast<const bf16x8*>(&lB[cur][(wc + n * 16 + r16) * 32 + kg * 8]);
#pragma unroll
    for (int m = 0; m < MR; ++m)
#pragma unroll
      for (int n = 0; n < 4; ++n)
        acc[m][n] = __builtin_amdgcn_mfma_f32_16x16x32_bf16(af[m], bfr[n], acc[m][n], 0, 0, 0);

    __syncthreads();
  }

#pragma unroll
  for (int m = 0; m < MR; ++m) {
    int row = bm + wr + m * 16 + kg * 4;
#pragma unroll
    for (int n = 0; n < 4; ++n) {
      int col = bn + wc + n * 16 + r16;
      float bv = bias[col];
#pragma unroll
      for (int j = 0; j < 4; ++j) {
        float v = acc[m][n][j] + bv;
        if (RELU) v = fmaxf(v, 0.f);
        if (OUTF32)
          Cf[(size_t)(row + j) * N + col] = v;
        else
          Cb[(size_t)(row + j) * N + col] = f2bf(v);
      }
    }
  }
}

// ---------------- V transpose via LDS: 64x64 tiles ----------------
__global__ __launch_bounds__(256) void vt_kern(const u16* __restrict__ src, int stride,
                                               int hmul, int hadd, u16* __restrict__ VT) {
  __shared__ u16 lt[64][72];
  const int bh = blockIdx.y;
  const int b = bh >> 4, h = bh & 15;
  const int s0 = blockIdx.x * 64;
  const u16* sb = src + (size_t)b * NS * stride + h * hmul + hadd;
#pragma unroll
  for (int c = 0; c < 2; ++c) {
    int chunk = c * 256 + threadIdx.x;
    int r = chunk >> 3, d = (chunk & 7) * 8;
    *reinterpret_cast<uint4*>(&lt[r][d]) =
        *reinterpret_cast<const uint4*>(&sb[(size_t)(s0 + r) * stride + d]);
  }
  __syncthreads();
  const int d = threadIdx.x >> 2, sq = (threadIdx.x & 3) * 16;
  union { u16 e[16]; uint4 v[2]; } pk;
#pragma unroll
  for (int i = 0; i < 16; ++i) pk.e[i] = lt[sq + i][d];
  uint4* dst = reinterpret_cast<uint4*>(&VT[((size_t)bh * NHD + d) * NS + s0 + sq]);
  dst[0] = pk.v[0];
  dst[1] = pk.v[1];
}

// ---------------- flash attention v10: per-qn PV, 48KB LDS (3 blocks/CU) ----------------
#define C1F 0.180336880f  // 0.125 * log2(e)
#define OPSZ ((size_t)32 * NS * NHD)

template <int CAUSAL>
__global__ __launch_bounds__(512) void attn10(const u16* __restrict__ Qp, int qstride,
                                              int qhm, const u16* __restrict__ Kp,
                                              int kstride, int khm, int kha,
                                              const u16* __restrict__ VT,
                                              u16* __restrict__ OP,
                                              float2* __restrict__ ML) {
  const int bid = blockIdx.x;              // 256
  const int split = blockIdx.y;            // 0/1
  const int xcd = bid & 7, j5 = bid >> 3;  // j5: 0..31
  const int bh = xcd + 8 * (j5 >> 3);      // 4 bh per XCD
  int qt = j5 & 7;
  if (CAUSAL) qt = 7 - qt;                 // heavy q-tiles first
  const int b = bh >> 4, h = bh & 15;
  const int tid = threadIdx.x, lane = tid & 63, wave = tid >> 6;  // 8 waves
  const int r16 = lane & 15, kg = lane >> 4;
  const int q0w = qt * 256 + wave * 32;

  __shared__ __align__(16) char lK[2][64 * 128];  // 16 KB (swizzled)
  __shared__ __align__(16) char lV[2][64 * 128];  // 16 KB (swizzled V^T)
  __shared__ __align__(16) char lP[8][16 * 128];  // 16 KB wave-private P (per-qn reuse)
  char* lPw = &lP[wave][0];

  const u16* qb = Qp + (size_t)b * NS * qstride + h * qhm;
  const u16* kb = Kp + (size_t)b * NS * kstride + h * khm + kha;
  const u16* vb = VT + (size_t)bh * NHD * NS;

  const int srow = tid >> 3;
  const int sbcol = (tid & 7) * 16;
  const int scol = (tid & 7) * 8;

  // Q fragments, pre-scaled by C1F
  bf16x8 qf[2][2];
#pragma unroll
  for (int qn = 0; qn < 2; ++qn)
#pragma unroll
    for (int ks = 0; ks < 2; ++ks) {
      bf16x8 v = *reinterpret_cast<const bf16x8*>(
          &qb[(size_t)(q0w + qn * 16 + r16) * qstride + ks * 32 + kg * 8]);
#pragma unroll
      for (int e = 0; e < 8; ++e) v[e] = (__bf16)((float)v[e] * C1F);
      qf[qn][ks] = v;
    }

  f32x4 o_acc[2][4] = {};
  float m_run[2] = {-1e30f, -1e30f}, l_lane[2] = {0.f, 0.f};

  const int ntb = CAUSAL ? (4 * qt + 4) : (NS / 64);
  const int wnt = CAUSAL ? (q0w / 64 + 1) : (NS / 64);
  const int halfb = (ntb + 1) >> 1;
  const int t0 = split ? halfb : 0;
  const int t1 = split ? ntb : halfb;

  uint4 kreg, vreg;
  auto ldregs = [&](int t) {
    const int kv0 = t * 64;
    kreg = *reinterpret_cast<const uint4*>(&kb[(size_t)(kv0 + srow) * kstride + scol]);
    vreg = *reinterpret_cast<const uint4*>(&vb[(size_t)srow * NS + kv0 + scol]);
  };
  auto wrlds = [&](int buf) {
    *reinterpret_cast<uint4*>(lswz(lK[buf], srow, sbcol)) = kreg;
    *reinterpret_cast<uint4*>(lswz(lV[buf], srow, sbcol)) = vreg;
  };

  ldregs(t0);
  wrlds(0);
  __syncthreads();

  for (int t = t0; t < t1; ++t) {
    const int cur = (t - t0) & 1;
    const bool more = (t + 1 < t1);
    if (more) ldregs(t + 1);

    if (t < wnt) {
      const int kv0 = t * 64;
      const char* lKc = lK[cur];
      const char* lVc = lV[cur];

      bf16x8 kf[8];
#pragma unroll
      for (int c = 0; c < 4; ++c)
#pragma unroll
        for (int ks = 0; ks < 2; ++ks)
          kf[c * 2 + ks] = *reinterpret_cast<const bf16x8*>(
              lswz(lKc, c * 16 + r16, ks * 64 + kg * 16));

      f32x4 s[2][4] = {};
#pragma unroll
      for (int c = 0; c < 4; ++c)
#pragma unroll
        for (int ks = 0; ks < 2; ++ks) {
          s[0][c] = __builtin_amdgcn_mfma_f32_16x16x32_bf16(kf[c * 2 + ks], qf[0][ks], s[0][c], 0, 0, 0);
          s[1][c] = __builtin_amdgcn_mfma_f32_16x16x32_bf16(kf[c * 2 + ks], qf[1][ks], s[1][c], 0, 0, 0);
        }

      bf16x8 vf[8];
#pragma unroll
      for (int cd = 0; cd < 4; ++cd)
#pragma unroll
        for (int ks = 0; ks < 2; ++ks)
          vf[cd * 2 + ks] = *reinterpret_cast<const bf16x8*>(
              lswz(lVc, cd * 16 + r16, ks * 64 + kg * 16));

#pragma unroll
      for (int qn = 0; qn < 2; ++qn) {
        if (CAUSAL && t == wnt - 1) {
          const int q = q0w + qn * 16 + r16;
#pragma unroll
          for (int c = 0; c < 4; ++c)
#pragma unroll
            for (int j = 0; j < 4; ++j)
              if (kv0 + c * 16 + kg * 4 + j > q) s[qn][c][j] = -1e31f;
        }
        float m0 = fmaxf(fmaxf(s[qn][0][0], s[qn][0][1]), fmaxf(s[qn][0][2], s[qn][0][3]));
        float m1 = fmaxf(fmaxf(s[qn][1][0], s[qn][1][1]), fmaxf(s[qn][1][2], s[qn][1][3]));
        float m2 = fmaxf(fmaxf(s[qn][2][0], s[qn][2][1]), fmaxf(s[qn][2][2], s[qn][2][3]));
        float m3 = fmaxf(fmaxf(s[qn][3][0], s[qn][3][1]), fmaxf(s[qn][3][2], s[qn][3][3]));
        float mxr = fmaxf(fmaxf(m0, m1), fmaxf(m2, m3));
        float mn = m_run[qn];
        if (!__all(mxr <= mn + 8.f)) {   // rescale: rare (defer-max T13)
          float mz = mxr;
          mz = fmaxf(mz, __shfl_xor(mz, 16));
          mz = fmaxf(mz, __shfl_xor(mz, 32));
          mn = fmaxf(m_run[qn], mz);
          const float cr = exp2f(m_run[qn] - mn);
          m_run[qn] = mn;
          l_lane[qn] *= cr;
          float crow[4];
#pragma unroll
          for (int j = 0; j < 4; ++j) crow[j] = __shfl(cr, kg * 4 + j);
#pragma unroll
          for (int cd = 0; cd < 4; ++cd)
#pragma unroll
            for (int j = 0; j < 4; ++j) o_acc[qn][cd][j] *= crow[j];
        }
        float su = 0.f;
#pragma unroll
        for (int c = 0; c < 4; ++c)
#pragma unroll
          for (int j = 0; j < 4; ++j) {
            float p = exp2f(s[qn][c][j] - mn);
            s[qn][c][j] = p;
            su += p;
          }
        l_lane[qn] += su;

        // P -> wave-private LDS (rows 0-15 reused per qn; in-wave DS order is safe)
#pragma unroll
        for (int c = 0; c < 4; ++c) {
          uint2 w2 = {pkbf(s[qn][c][0], s[qn][c][1]), pkbf(s[qn][c][2], s[qn][c][3])};
          *reinterpret_cast<uint2*>(lswz(lPw, r16, c * 32 + kg * 8)) = w2;
        }
        bf16x8 pf[2];
#pragma unroll
        for (int ks = 0; ks < 2; ++ks)
          pf[ks] = *reinterpret_cast<const bf16x8*>(
              lswz(lPw, r16, ks * 64 + kg * 16));
#pragma unroll
        for (int cd = 0; cd < 4; ++cd)
#pragma unroll
          for (int ks = 0; ks < 2; ++ks)
            o_acc[qn][cd] = __builtin_amdgcn_mfma_f32_16x16x32_bf16(
                pf[ks], vf[cd * 2 + ks], o_acc[qn][cd], 0, 0, 0);
      }
    }

    if (more) wrlds(cur ^ 1);
    __syncthreads();
  }

  // epilogue: un-normalized partials + (m, l)
  u16* op = OP + split * OPSZ + (size_t)bh * NS * NHD;
#pragma unroll
  for (int qn = 0; qn < 2; ++qn) {
    float l = l_lane[qn];
    l += __shfl_xor(l, 16);
    l += __shfl_xor(l, 32);
#pragma unroll
    for (int cd = 0; cd < 4; ++cd) {
      int col = cd * 16 + r16;
#pragma unroll
      for (int j = 0; j < 4; ++j) {
        int row = q0w + qn * 16 + kg * 4 + j;
        op[(size_t)row * NHD + col] = f2bf(o_acc[qn][cd][j]);
      }
    }
    if (kg == 0)
      ML[(size_t)split * 32 * NS + (size_t)bh * NS + q0w + qn * 16 + r16] =
          make_float2(m_run[qn], l);
  }
}

// ---------------- combine the two KV-splits ----------------
__global__ __launch_bounds__(256) void attn_comb(const u16* __restrict__ OP,
                                                 const float2* __restrict__ ML,
                                                 u16* __restrict__ AO) {
  int idx = blockIdx.x * 256 + threadIdx.x;   // 524288
  int dg = (idx & 7) * 8;
  int q = (idx >> 3) & (NS - 1);
  int bh = idx >> 14;
  int b = bh >> 4, h = bh & 15;
  float2 ml0 = ML[(size_t)bh * NS + q];
  float2 ml1 = ML[(size_t)32 * NS + (size_t)bh * NS + q];
  float M = fmaxf(ml0.x, ml1.x);
  float w0 = exp2f(ml0.x - M), w1 = exp2f(ml1.x - M);
  float linv = 1.f / (ml0.y * w0 + ml1.y * w1);
  w0 *= linv;
  w1 *= linv;
  size_t src = ((size_t)bh * NS + q) * NHD + dg;
  uint4 r0 = *reinterpret_cast<const uint4*>(&OP[src]);
  uint4 r1 = *reinterpret_cast<const uint4*>(&OP[OPSZ + src]);
  const u16* e0 = reinterpret_cast<const u16*>(&r0);
  const u16* e1 = reinterpret_cast<const u16*>(&r1);
  u16 out[8];
#pragma unroll
  for (int j = 0; j < 8; ++j)
    out[j] = f2bf(bf2f(e0[j]) * w0 + bf2f(e1[j]) * w1);
  *reinterpret_cast<uint4*>(&AO[((size_t)b * NS + q) * ND + h * NHD + dg]) =
      *reinterpret_cast<uint4*>(out);
}

// ---------------- fused residual + LayerNorm ----------------
__global__ __launch_bounds__(256) void ln_kern(const float* __restrict__ a,
                                               const float* __restrict__ resid,
                                               const float* __restrict__ g,
                                               const float* __restrict__ bb,
                                               float* __restrict__ outf,
                                               u16* __restrict__ outb) {
  const int row = blockIdx.x;
  const int tid = threadIdx.x;
  const size_t off = (size_t)row * ND + tid * 4;
  f32x4 v = *reinterpret_cast<const f32x4*>(&a[off]);
  f32x4 r = *reinterpret_cast<const f32x4*>(&resid[off]);
#pragma unroll
  for (int j = 0; j < 4; ++j) v[j] += r[j];
  float s = v[0] + v[1] + v[2] + v[3];
  float s2 = v[0] * v[0] + v[1] * v[1] + v[2] * v[2] + v[3] * v[3];
#pragma unroll
  for (int m = 1; m < 64; m <<= 1) {
    s += __shfl_xor(s, m);
    s2 += __shfl_xor(s2, m);
  }
  __shared__ float ws1[4], ws2[4];
  int wave = tid >> 6, lane = tid & 63;
  if (lane == 0) { ws1[wave] = s; ws2[wave] = s2; }
  __syncthreads();
  s = ws1[0] + ws1[1] + ws1[2] + ws1[3];
  s2 = ws2[0] + ws2[1] + ws2[2] + ws2[3];
  float mean = s * (1.f / ND);
  float var = fmaxf(s2 * (1.f / ND) - mean * mean, 0.f);
  float rstd = rsqrtf(var + 1e-9f);
  f32x4 gg = *reinterpret_cast<const f32x4*>(&g[tid * 4]);
  f32x4 bv = *reinterpret_cast<const f32x4*>(&bb[tid * 4]);
  f32x4 o;
  u16x4 ob;
#pragma unroll
  for (int j = 0; j < 4; ++j) {
    o[j] = gg[j] * (v[j] - mean) * rstd + bv[j];
    ob[j] = f2bf(o[j]);
  }
  *reinterpret_cast<f32x4*>(&outf[off]) = o;
  *reinterpret_cast<u16x4*>(&outb[off]) = ob;
}

// ---------------- host launch ----------------
extern "C" void kernel_launch(void* const* d_in, const int* in_sizes, int n_in,
                              void* d_out, int out_size, void* d_ws, size_t ws_size,
                              hipStream_t stream) {
  const float* x = (const float*)d_in[0];
  const float* y = (const float*)d_in[1];
  const float* qkv_w = (const float*)d_in[3];
  const float* qkv_b = (const float*)d_in[4];
  const float* sa_fc_w = (const float*)d_in[5];
  const float* sa_fc_b = (const float*)d_in[6];
  const float* g1 = (const float*)d_in[7];
  const float* b1 = (const float*)d_in[8];
  const float* kv_w = (const float*)d_in[9];
  const float* kv_b = (const float*)d_in[10];
  const float* q_w = (const float*)d_in[11];
  const float* q_b = (const float*)d_in[12];
  const float* ca_fc_w = (const float*)d_in[13];
  const float* ca_fc_b = (const float*)d_in[14];
  const float* g2 = (const float*)d_in[15];
  const float* b2 = (const float*)d_in[16];
  const float* ff1_w = (const float*)d_in[17];
  const float* ff1_b = (const float*)d_in[18];
  const float* ff2_w = (const float*)d_in[19];
  const float* ff2_b = (const float*)d_in[20];
  const float* g3 = (const float*)d_in[21];
  const float* b3 = (const float*)d_in[22];

  if (ws_size < (120ull << 20)) return;

  char* w = (char*)d_ws;
  // weight arena 0..32MB (bf16, transposed [N,K])
  u16* Wqkv = (u16*)w;                      // 3072x1024
  u16* Wsa  = Wqkv + 3145728;               // 1024x1024
  u16* Wkv  = Wsa + 1048576;                // 2048x1024
  u16* Wq   = Wkv + 2097152;                // 1024x1024
  u16* Wca  = Wq + 1048576;                 // 1024x1024
  u16* Wff1 = Wca + 1048576;                // 4096x1024
  u16* Wff2 = Wff1 + 4194304;               // 1024x4096
  u16* ACT = (u16*)(w + (32ull << 20));     // 8 MB (ML aliases during attn)
  u16* XB  = (u16*)(w + (40ull << 20));     // 8 MB (H=ff1-out spans 40..72 during FFN)
  u16* Qb  = (u16*)(w + (48ull << 20));     // 8 MB
  u16* VT  = (u16*)(w + (56ull << 20));     // 8 MB
  u16* G   = (u16*)(w + (64ull << 20));     // 24 MB (AO aliases G[0:8MB] after attn)
  float* Fa = (float*)(w + (88ull << 20));  // 16 MB (OP partials alias during attn)
  float* Fb = (float*)(w + (104ull << 20)); // 16 MB residual
  u16* H   = XB;                            // ff1 out 32MB (XB..G head, dead in FFN)
  u16* AO  = G;                             // attn out aliases G head
  u16* OPb = (u16*)Fa;
  float2* ML = (float2*)ACT;
  float* OUT = (float*)d_out;

  dim3 wblk(32, 8);
  const int n4act = NBS * ND / 4;

  // ---- prep: input converts + ALL weight transposes (one kernel) ----
  conv_bf16<<<n4act / 256, 256, 0, stream>>>(y, ACT, n4act);
  conv_bf16<<<n4act / 256, 256, 0, stream>>>(x, XB, n4act);
  WAll wa;
  wa.s[0] = {qkv_w, Wqkv, 3 * ND, 0};        // 3072 tiles
  wa.s[1] = {sa_fc_w, Wsa, ND, 3072};        // 1024
  wa.s[2] = {kv_w, Wkv, 2 * ND, 4096};       // 2048
  wa.s[3] = {q_w, Wq, ND, 6144};             // 1024
  wa.s[4] = {ca_fc_w, Wca, ND, 7168};        // 1024
  wa.s[5] = {ff1_w, Wff1, NFF, 8192};        // 4096
  wa.s[6] = {ff2_w, Wff2, ND, 12288};        // 4096 (K=4096)
  wconv_all<<<16384, wblk, 0, stream>>>(wa);

  // ---- self attention block ----
  gemm_bt<128, 0, 0><<<dim3(3 * ND / 128, NBS / 128), 256, 0, stream>>>(
      ACT, Wqkv, qkv_b, nullptr, G, NBS, 3 * ND, ND);
  vt_kern<<<dim3(NS / 64, NB * NH), 256, 0, stream>>>(G, 3 * ND, 192, 128, VT);
  attn10<1><<<dim3(256, 2), 512, 0, stream>>>(G, 3 * ND, 192, G, 3 * ND, 192, 64, VT, OPb, ML);
  attn_comb<<<2048, 256, 0, stream>>>(OPb, ML, AO);
  gemm_bt<64, 1, 0><<<dim3(ND / 128, NBS / 64), 256, 0, stream>>>(
      AO, Wsa, sa_fc_b, Fa, nullptr, NBS, ND, ND);
  ln_kern<<<NBS, 256, 0, stream>>>(Fa, y, g1, b1, Fb, ACT);  // y1

  // ---- cross attention block ----
  gemm_bt<128, 0, 0><<<dim3(2 * ND / 128, NBS / 128), 256, 0, stream>>>(
      XB, Wkv, kv_b, nullptr, G, NBS, 2 * ND, ND);
  vt_kern<<<dim3(NS / 64, NB * NH), 256, 0, stream>>>(G, 2 * ND, 128, 64, VT);
  gemm_bt<64, 0, 0><<<dim3(ND / 128, NBS / 64), 256, 0, stream>>>(
      ACT, Wq, q_b, nullptr, Qb, NBS, ND, ND);
  attn10<0><<<dim3(256, 2), 512, 0, stream>>>(Qb, ND, 64, G, 2 * ND, 128, 0, VT, OPb, ML);
  attn_comb<<<2048, 256, 0, stream>>>(OPb, ML, AO);
  gemm_bt<64, 1, 0><<<dim3(ND / 128, NBS / 64), 256, 0, stream>>>(
      AO, Wca, ca_fc_b, Fa, nullptr, NBS, ND, ND);
  ln_kern<<<NBS, 256, 0, stream>>>(Fa, Fb, g2, b2, Fb, ACT);  // y2 (in-place resid)

  // ---- FFN ----
  gemm_bt<128, 0, 1><<<dim3(NFF / 128, NBS / 128), 256, 0, stream>>>(
      ACT, Wff1, ff1_b, nullptr, H, NBS, NFF, ND);
  gemm_bt<64, 1, 0><<<dim3(ND / 128, NBS / 64), 256, 0, stream>>>(
      H, Wff2, ff2_b, Fa, nullptr, NBS, ND, NFF);
  ln_kern<<<NBS, 256, 0, stream>>>(Fa, Fb, g3, b3, OUT, ACT);
}

// Round 11
// 462.576 us; speedup vs baseline: 2.3709x; 1.0072x over previous
//
#include <hip/hip_runtime.h>

typedef unsigned short u16;
typedef unsigned int u32;
typedef __attribute__((ext_vector_type(4))) float f32x4;
typedef __attribute__((ext_vector_type(8))) __bf16 bf16x8;
typedef __attribute__((ext_vector_type(2))) __bf16 bf16x2;
typedef __attribute__((ext_vector_type(4))) u16 u16x4;

#define NB 2
#define NS 2048
#define ND 1024
#define NH 16
#define NHD 64
#define NFF 4096
#define NBS (NB * NS)   // 4096 rows

typedef const __attribute__((address_space(1))) unsigned int as1_u32;
typedef __attribute__((address_space(3))) unsigned int as3_u32;

__device__ __forceinline__ void gl_lds16(const u16* g, u16* l) {
  __builtin_amdgcn_global_load_lds((as1_u32*)g, (as3_u32*)l, 16, 0, 0);
}

__device__ __forceinline__ u16 f2bf(float f) {
  union { float f; unsigned u; } v; v.f = f;
  unsigned r = (v.u + 0x7FFFu + ((v.u >> 16) & 1u)) >> 16;  // RNE
  return (u16)r;
}

__device__ __forceinline__ float bf2f(u16 u) {
  union { u32 u; float f; } v; v.u = ((u32)u) << 16; return v.f;
}

__device__ __forceinline__ u32 pkbf(float a, float b) {
  bf16x2 v; v[0] = (__bf16)a; v[1] = (__bf16)b;
  union { bf16x2 v; u32 u; } c; c.v = v; return c.u;
}

// XOR-swizzled LDS addressing (pitch 128B): bank-conflict-free for row-strided
// b128 fragment reads; XOR flips only bit 4 so 8B/16B alignment is preserved.
__device__ __forceinline__ char* lswz(void* base, int row, int bcol) {
  return (char*)base + row * 128 + (bcol ^ ((row & 7) << 4));
}
__device__ __forceinline__ const char* lswz(const void* base, int row, int bcol) {
  return (const char*)base + row * 128 + (bcol ^ ((row & 7) << 4));
}

// ---------------- f32 -> bf16 (vectorized) ----------------
__global__ __launch_bounds__(256) void conv_bf16(const float* __restrict__ in,
                                                 u16* __restrict__ out, int n4) {
  int i = blockIdx.x * 256 + threadIdx.x;
  if (i >= n4) return;
  f32x4 v = *reinterpret_cast<const f32x4*>(&in[(size_t)i * 4]);
  u16x4 o;
#pragma unroll
  for (int j = 0; j < 4; ++j) o[j] = f2bf(v[j]);
  *reinterpret_cast<u16x4*>(&out[(size_t)i * 4]) = o;
}

// ---------------- ALL weight converts+transposes in ONE kernel ----------------
struct WSeg { const float* src; u16* dst; int N; int tile0; };
struct WAll { WSeg s[7]; };

__global__ void wconv_all(WAll wa) {
  __shared__ float t[32][33];
  int bid = blockIdx.x;
  int si = 0;
#pragma unroll
  for (int i = 1; i < 7; ++i) si += (bid >= wa.s[i].tile0) ? 1 : 0;
  const WSeg sg = wa.s[si];
  const int tt = bid - sg.tile0;
  const int tilesx = sg.N >> 5;
  const int n0 = (tt % tilesx) * 32, k0 = (tt / tilesx) * 32;
  const int K = (si == 6) ? NFF : ND;
  int tx = threadIdx.x, ty = threadIdx.y;  // 32 x 8
#pragma unroll
  for (int i = ty; i < 32; i += 8) t[i][tx] = sg.src[(size_t)(k0 + i) * sg.N + n0 + tx];
  __syncthreads();
#pragma unroll
  for (int i = ty; i < 32; i += 8)
    sg.dst[(size_t)(n0 + i) * K + k0 + tx] = f2bf(t[tx][i]);
}

// ---------------- GEMM, 2-phase double-buffered + XCD-chunked swizzle (T1) ----------------
template <int TM, int OUTF32, int RELU>
__global__ __launch_bounds__(256) void gemm_bt(const u16* __restrict__ A,
                                               const u16* __restrict__ BT,
                                               const float* __restrict__ bias,
                                               float* __restrict__ Cf,
                                               u16* __restrict__ Cb,
                                               int M, int N, int K) {
  constexpr int MR = TM / 32;
  constexpr int ACH = TM / 64;
  __shared__ __align__(16) u16 lA[2][TM * 32];
  __shared__ __align__(16) u16 lB[2][128 * 32];
  const int tid = threadIdx.x;
  const int lane = tid & 63, wave = tid >> 6;
  // T1: chunk the flattened grid per XCD so same-A-panel blocks share one L2.
  const u32 gx = gridDim.x;
  const u32 nwg = gx * gridDim.y;
  const u32 flat = blockIdx.y * gx + blockIdx.x;
  const u32 swz = (flat & 7) * (nwg >> 3) + (flat >> 3);   // nwg % 8 == 0 for all launches
  const int bm = (swz / gx) * TM, bn = (swz % gx) * 128;
  const int wr = (wave >> 1) * (MR * 16), wc = (wave & 1) * 64;
  const int r16 = lane & 15, kg = lane >> 4;

  f32x4 acc[MR][4] = {};

  auto stage = [&](int buf, int k0) {
#pragma unroll
    for (int c = 0; c < ACH; ++c) {
      int chunk = c * 256 + tid;
      int r = chunk >> 2, kc = (chunk & 3) * 8;
      gl_lds16(&A[(size_t)(bm + r) * K + k0 + kc], &lA[buf][(c * 256 + wave * 64) * 8]);
    }
#pragma unroll
    for (int c = 0; c < 2; ++c) {
      int chunk = c * 256 + tid;
      int r = chunk >> 2, kc = (chunk & 3) * 8;
      gl_lds16(&BT[(size_t)(bn + r) * K + k0 + kc], &lB[buf][(c * 256 + wave * 64) * 8]);
    }
  };

  stage(0, 0);
  __syncthreads();

  const int nk = K / 32;
  for (int i = 0; i < nk; ++i) {
    const int cur = i & 1;
    if (i + 1 < nk) stage(cur ^ 1, (i + 1) * 32);

    bf16x8 af[MR], bfr[4];
#pragma unroll
    for (int m = 0; m < MR; ++m)
      af[m] = *reinterpret_cast<const bf16x8*>(&lA[cur][(wr + m * 16 + r16) * 32 + kg * 8]);
#pragma unroll
    for (int n = 0; n < 4; ++n)
      bfr[n] = *reinterpret_cast<const bf16x8*>(&lB[cur][(wc + n * 16 + r16) * 32 + kg * 8]);
    __builtin_amdgcn_s_setprio(1);
#pragma unroll
    for (int m = 0; m < MR; ++m)
#pragma unroll
      for (int n = 0; n < 4; ++n)
        acc[m][n] = __builtin_amdgcn_mfma_f32_16x16x32_bf16(af[m], bfr[n], acc[m][n], 0, 0, 0);
    __builtin_amdgcn_s_setprio(0);

    __syncthreads();
  }

#pragma unroll
  for (int m = 0; m < MR; ++m) {
    int row = bm + wr + m * 16 + kg * 4;
#pragma unroll
    for (int n = 0; n < 4; ++n) {
      int col = bn + wc + n * 16 + r16;
      float bv = bias[col];
#pragma unroll
      for (int j = 0; j < 4; ++j) {
        float v = acc[m][n][j] + bv;
        if (RELU) v = fmaxf(v, 0.f);
        if (OUTF32)
          Cf[(size_t)(row + j) * N + col] = v;
        else
          Cb[(size_t)(row + j) * N + col] = f2bf(v);
      }
    }
  }
}

// ---------------- V transpose via LDS: 64x64 tiles ----------------
__global__ __launch_bounds__(256) void vt_kern(const u16* __restrict__ src, int stride,
                                               int hmul, int hadd, u16* __restrict__ VT) {
  __shared__ u16 lt[64][72];
  const int bh = blockIdx.y;
  const int b = bh >> 4, h = bh & 15;
  const int s0 = blockIdx.x * 64;
  const u16* sb = src + (size_t)b * NS * stride + h * hmul + hadd;
#pragma unroll
  for (int c = 0; c < 2; ++c) {
    int chunk = c * 256 + threadIdx.x;
    int r = chunk >> 3, d = (chunk & 7) * 8;
    *reinterpret_cast<uint4*>(&lt[r][d]) =
        *reinterpret_cast<const uint4*>(&sb[(size_t)(s0 + r) * stride + d]);
  }
  __syncthreads();
  const int d = threadIdx.x >> 2, sq = (threadIdx.x & 3) * 16;
  union { u16 e[16]; uint4 v[2]; } pk;
#pragma unroll
  for (int i = 0; i < 16; ++i) pk.e[i] = lt[sq + i][d];
  uint4* dst = reinterpret_cast<uint4*>(&VT[((size_t)bh * NHD + d) * NS + s0 + sq]);
  dst[0] = pk.v[0];
  dst[1] = pk.v[1];
}

// ---------------- flash attention v11: l-sum via MFMA-ones, setprio, N-way split ----------------
#define C1F 0.180336880f  // 0.125 * log2(e)
#define OPSZ ((size_t)32 * NS * NHD)

template <int CAUSAL, int SPLITS>
__global__ __launch_bounds__(512) void attn11(const u16* __restrict__ Qp, int qstride,
                                              int qhm, const u16* __restrict__ Kp,
                                              int kstride, int khm, int kha,
                                              const u16* __restrict__ VT,
                                              u16* __restrict__ OP,
                                              float2* __restrict__ ML) {
  const int bid = blockIdx.x;              // 256
  const int split = blockIdx.y;            // 0..SPLITS-1
  const int xcd = bid & 7, j5 = bid >> 3;  // j5: 0..31
  const int bh = xcd + 8 * (j5 >> 3);      // 4 bh per XCD
  int qt = j5 & 7;
  if (CAUSAL) qt = 7 - qt;                 // heavy q-tiles first
  const int b = bh >> 4, h = bh & 15;
  const int tid = threadIdx.x, lane = tid & 63, wave = tid >> 6;  // 8 waves
  const int r16 = lane & 15, kg = lane >> 4;
  const int q0w = qt * 256 + wave * 32;

  __shared__ __align__(16) char lK[2][64 * 128];
  __shared__ __align__(16) char lV[2][64 * 128];
  __shared__ __align__(16) char lP[8][16 * 128];
  char* lPw = &lP[wave][0];

  const u16* qb = Qp + (size_t)b * NS * qstride + h * qhm;
  const u16* kb = Kp + (size_t)b * NS * kstride + h * khm + kha;
  const u16* vb = VT + (size_t)bh * NHD * NS;

  const int srow = tid >> 3;
  const int sbcol = (tid & 7) * 16;
  const int scol = (tid & 7) * 8;

  // Q fragments, pre-scaled by C1F
  bf16x8 qf[2][2];
#pragma unroll
  for (int qn = 0; qn < 2; ++qn)
#pragma unroll
    for (int ks = 0; ks < 2; ++ks) {
      bf16x8 v = *reinterpret_cast<const bf16x8*>(
          &qb[(size_t)(q0w + qn * 16 + r16) * qstride + ks * 32 + kg * 8]);
#pragma unroll
      for (int e = 0; e < 8; ++e) v[e] = (__bf16)((float)v[e] * C1F);
      qf[qn][ks] = v;
    }

  bf16x8 onesf;
#pragma unroll
  for (int e = 0; e < 8; ++e) onesf[e] = (__bf16)1.0f;

  f32x4 o_acc[2][4] = {};
  f32x4 l_acc[2] = {};                     // row-sums via P x ones MFMA
  float m_run[2] = {-1e30f, -1e30f};

  const int ntb = CAUSAL ? (4 * qt + 4) : (NS / 64);   // divisible by SPLITS
  const int wnt = CAUSAL ? (q0w / 64 + 1) : (NS / 64);
  const int t0 = (split * ntb) / SPLITS;
  const int t1 = ((split + 1) * ntb) / SPLITS;

  uint4 kreg, vreg;
  auto ldregs = [&](int t) {
    const int kv0 = t * 64;
    kreg = *reinterpret_cast<const uint4*>(&kb[(size_t)(kv0 + srow) * kstride + scol]);
    vreg = *reinterpret_cast<const uint4*>(&vb[(size_t)srow * NS + kv0 + scol]);
  };
  auto wrlds = [&](int buf) {
    *reinterpret_cast<uint4*>(lswz(lK[buf], srow, sbcol)) = kreg;
    *reinterpret_cast<uint4*>(lswz(lV[buf], srow, sbcol)) = vreg;
  };

  ldregs(t0);
  wrlds(0);
  __syncthreads();

  for (int t = t0; t < t1; ++t) {
    const int cur = (t - t0) & 1;
    const bool more = (t + 1 < t1);
    if (more) ldregs(t + 1);

    if (t < wnt) {
      const int kv0 = t * 64;
      const char* lKc = lK[cur];
      const char* lVc = lV[cur];

      bf16x8 kf[8];
#pragma unroll
      for (int c = 0; c < 4; ++c)
#pragma unroll
        for (int ks = 0; ks < 2; ++ks)
          kf[c * 2 + ks] = *reinterpret_cast<const bf16x8*>(
              lswz(lKc, c * 16 + r16, ks * 64 + kg * 16));

      f32x4 s[2][4] = {};
      __builtin_amdgcn_s_setprio(1);
#pragma unroll
      for (int c = 0; c < 4; ++c)
#pragma unroll
        for (int ks = 0; ks < 2; ++ks) {
          s[0][c] = __builtin_amdgcn_mfma_f32_16x16x32_bf16(kf[c * 2 + ks], qf[0][ks], s[0][c], 0, 0, 0);
          s[1][c] = __builtin_amdgcn_mfma_f32_16x16x32_bf16(kf[c * 2 + ks], qf[1][ks], s[1][c], 0, 0, 0);
        }
      __builtin_amdgcn_s_setprio(0);

      bf16x8 vf[8];
#pragma unroll
      for (int cd = 0; cd < 4; ++cd)
#pragma unroll
        for (int ks = 0; ks < 2; ++ks)
          vf[cd * 2 + ks] = *reinterpret_cast<const bf16x8*>(
              lswz(lVc, cd * 16 + r16, ks * 64 + kg * 16));

#pragma unroll
      for (int qn = 0; qn < 2; ++qn) {
        if (CAUSAL && t == wnt - 1) {
          const int q = q0w + qn * 16 + r16;
#pragma unroll
          for (int c = 0; c < 4; ++c)
#pragma unroll
            for (int j = 0; j < 4; ++j)
              if (kv0 + c * 16 + kg * 4 + j > q) s[qn][c][j] = -1e31f;
        }
        float m0 = fmaxf(fmaxf(s[qn][0][0], s[qn][0][1]), fmaxf(s[qn][0][2], s[qn][0][3]));
        float m1 = fmaxf(fmaxf(s[qn][1][0], s[qn][1][1]), fmaxf(s[qn][1][2], s[qn][1][3]));
        float m2 = fmaxf(fmaxf(s[qn][2][0], s[qn][2][1]), fmaxf(s[qn][2][2], s[qn][2][3]));
        float m3 = fmaxf(fmaxf(s[qn][3][0], s[qn][3][1]), fmaxf(s[qn][3][2], s[qn][3][3]));
        float mxr = fmaxf(fmaxf(m0, m1), fmaxf(m2, m3));
        float mn = m_run[qn];
        if (!__all(mxr <= mn + 8.f)) {   // rescale: rare (defer-max T13)
          float mz = mxr;
          mz = fmaxf(mz, __shfl_xor(mz, 16));
          mz = fmaxf(mz, __shfl_xor(mz, 32));
          mn = fmaxf(m_run[qn], mz);
          const float cr = exp2f(m_run[qn] - mn);
          m_run[qn] = mn;
          float crow[4];
#pragma unroll
          for (int j = 0; j < 4; ++j) crow[j] = __shfl(cr, kg * 4 + j);
#pragma unroll
          for (int cd = 0; cd < 4; ++cd)
#pragma unroll
            for (int j = 0; j < 4; ++j) o_acc[qn][cd][j] *= crow[j];
#pragma unroll
          for (int j = 0; j < 4; ++j) l_acc[qn][j] *= crow[j];
        }
#pragma unroll
        for (int c = 0; c < 4; ++c)
#pragma unroll
          for (int j = 0; j < 4; ++j)
            s[qn][c][j] = exp2f(s[qn][c][j] - mn);

        // P -> wave-private LDS (rows 0-15 reused per qn)
#pragma unroll
        for (int c = 0; c < 4; ++c) {
          uint2 w2 = {pkbf(s[qn][c][0], s[qn][c][1]), pkbf(s[qn][c][2], s[qn][c][3])};
          *reinterpret_cast<uint2*>(lswz(lPw, r16, c * 32 + kg * 8)) = w2;
        }
        bf16x8 pf[2];
#pragma unroll
        for (int ks = 0; ks < 2; ++ks)
          pf[ks] = *reinterpret_cast<const bf16x8*>(lswz(lPw, r16, ks * 64 + kg * 16));

        __builtin_amdgcn_s_setprio(1);
        // row-sums: l_acc[j] = sum_k P[row=kg*4+j][k]  (aligned with o_acc rows)
        l_acc[qn] = __builtin_amdgcn_mfma_f32_16x16x32_bf16(pf[0], onesf, l_acc[qn], 0, 0, 0);
        l_acc[qn] = __builtin_amdgcn_mfma_f32_16x16x32_bf16(pf[1], onesf, l_acc[qn], 0, 0, 0);
#pragma unroll
        for (int cd = 0; cd < 4; ++cd)
#pragma unroll
          for (int ks = 0; ks < 2; ++ks)
            o_acc[qn][cd] = __builtin_amdgcn_mfma_f32_16x16x32_bf16(
                pf[ks], vf[cd * 2 + ks], o_acc[qn][cd], 0, 0, 0);
        __builtin_amdgcn_s_setprio(0);
      }
    }

    if (more) wrlds(cur ^ 1);
    __syncthreads();
  }

  // epilogue: un-normalized partials + (m, l); l already row-aligned
  u16* op = OP + split * OPSZ + (size_t)bh * NS * NHD;
#pragma unroll
  for (int qn = 0; qn < 2; ++qn) {
    float mrow[4];
#pragma unroll
    for (int j = 0; j < 4; ++j) mrow[j] = __shfl(m_run[qn], kg * 4 + j);
#pragma unroll
    for (int cd = 0; cd < 4; ++cd) {
      int col = cd * 16 + r16;
#pragma unroll
      for (int j = 0; j < 4; ++j) {
        int row = q0w + qn * 16 + kg * 4 + j;
        op[(size_t)row * NHD + col] = f2bf(o_acc[qn][cd][j]);
      }
    }
    if (r16 == 0) {
#pragma unroll
      for (int j = 0; j < 4; ++j)
        ML[((size_t)(split * 32 + bh)) * NS + q0w + qn * 16 + kg * 4 + j] =
            make_float2(mrow[j], l_acc[qn][j]);
    }
  }
}

// ---------------- combine the KV-splits ----------------
template <int NSPL>
__global__ __launch_bounds__(256) void attn_comb(const u16* __restrict__ OP,
                                                 const float2* __restrict__ ML,
                                                 u16* __restrict__ AO) {
  int idx = blockIdx.x * 256 + threadIdx.x;   // 524288
  int dg = (idx & 7) * 8;
  int q = (idx >> 3) & (NS - 1);
  int bh = idx >> 14;
  int b = bh >> 4, h = bh & 15;
  float2 ml[NSPL];
  float M = -1e30f;
#pragma unroll
  for (int s = 0; s < NSPL; ++s) {
    ml[s] = ML[((size_t)(s * 32 + bh)) * NS + q];
    M = fmaxf(M, ml[s].x);
  }
  float wgt[NSPL], wsum = 0.f;
#pragma unroll
  for (int s = 0; s < NSPL; ++s) {
    wgt[s] = exp2f(ml[s].x - M);
    wsum += ml[s].y * wgt[s];
  }
  float linv = 1.f / wsum;
  size_t src = ((size_t)bh * NS + q) * NHD + dg;
  float acc[8] = {};
#pragma unroll
  for (int s = 0; s < NSPL; ++s) {
    uint4 r = *reinterpret_cast<const uint4*>(&OP[s * OPSZ + src]);
    const u16* e = reinterpret_cast<const u16*>(&r);
#pragma unroll
    for (int j = 0; j < 8; ++j) acc[j] += bf2f(e[j]) * wgt[s];
  }
  u16 out[8];
#pragma unroll
  for (int j = 0; j < 8; ++j) out[j] = f2bf(acc[j] * linv);
  *reinterpret_cast<uint4*>(&AO[((size_t)b * NS + q) * ND + h * NHD + dg]) =
      *reinterpret_cast<uint4*>(out);
}

// ---------------- fused residual + LayerNorm ----------------
__global__ __launch_bounds__(256) void ln_kern(const float* __restrict__ a,
                                               const float* __restrict__ resid,
                                               const float* __restrict__ g,
                                               const float* __restrict__ bb,
                                               float* __restrict__ outf,
                                               u16* __restrict__ outb) {
  const int row = blockIdx.x;
  const int tid = threadIdx.x;
  const size_t off = (size_t)row * ND + tid * 4;
  f32x4 v = *reinterpret_cast<const f32x4*>(&a[off]);
  f32x4 r = *reinterpret_cast<const f32x4*>(&resid[off]);
#pragma unroll
  for (int j = 0; j < 4; ++j) v[j] += r[j];
  float s = v[0] + v[1] + v[2] + v[3];
  float s2 = v[0] * v[0] + v[1] * v[1] + v[2] * v[2] + v[3] * v[3];
#pragma unroll
  for (int m = 1; m < 64; m <<= 1) {
    s += __shfl_xor(s, m);
    s2 += __shfl_xor(s2, m);
  }
  __shared__ float ws1[4], ws2[4];
  int wave = tid >> 6, lane = tid & 63;
  if (lane == 0) { ws1[wave] = s; ws2[wave] = s2; }
  __syncthreads();
  s = ws1[0] + ws1[1] + ws1[2] + ws1[3];
  s2 = ws2[0] + ws2[1] + ws2[2] + ws2[3];
  float mean = s * (1.f / ND);
  float var = fmaxf(s2 * (1.f / ND) - mean * mean, 0.f);
  float rstd = rsqrtf(var + 1e-9f);
  f32x4 gg = *reinterpret_cast<const f32x4*>(&g[tid * 4]);
  f32x4 bv = *reinterpret_cast<const f32x4*>(&bb[tid * 4]);
  f32x4 o;
  u16x4 ob;
#pragma unroll
  for (int j = 0; j < 4; ++j) {
    o[j] = gg[j] * (v[j] - mean) * rstd + bv[j];
    ob[j] = f2bf(o[j]);
  }
  *reinterpret_cast<f32x4*>(&outf[off]) = o;
  *reinterpret_cast<u16x4*>(&outb[off]) = ob;
}

// ---------------- host launch ----------------
extern "C" void kernel_launch(void* const* d_in, const int* in_sizes, int n_in,
                              void* d_out, int out_size, void* d_ws, size_t ws_size,
                              hipStream_t stream) {
  const float* x = (const float*)d_in[0];
  const float* y = (const float*)d_in[1];
  const float* qkv_w = (const float*)d_in[3];
  const float* qkv_b = (const float*)d_in[4];
  const float* sa_fc_w = (const float*)d_in[5];
  const float* sa_fc_b = (const float*)d_in[6];
  const float* g1 = (const float*)d_in[7];
  const float* b1 = (const float*)d_in[8];
  const float* kv_w = (const float*)d_in[9];
  const float* kv_b = (const float*)d_in[10];
  const float* q_w = (const float*)d_in[11];
  const float* q_b = (const float*)d_in[12];
  const float* ca_fc_w = (const float*)d_in[13];
  const float* ca_fc_b = (const float*)d_in[14];
  const float* g2 = (const float*)d_in[15];
  const float* b2 = (const float*)d_in[16];
  const float* ff1_w = (const float*)d_in[17];
  const float* ff1_b = (const float*)d_in[18];
  const float* ff2_w = (const float*)d_in[19];
  const float* ff2_b = (const float*)d_in[20];
  const float* g3 = (const float*)d_in[21];
  const float* b3 = (const float*)d_in[22];

  if (ws_size < (120ull << 20)) return;

  char* w = (char*)d_ws;
  // weight arena 0..32MB (bf16, transposed [N,K])
  u16* Wqkv = (u16*)w;                      // 3072x1024
  u16* Wsa  = Wqkv + 3145728;               // 1024x1024
  u16* Wkv  = Wsa + 1048576;                // 2048x1024
  u16* Wq   = Wkv + 2097152;                // 1024x1024
  u16* Wca  = Wq + 1048576;                 // 1024x1024
  u16* Wff1 = Wca + 1048576;                // 4096x1024
  u16* Wff2 = Wff1 + 4194304;               // 1024x4096
  u16* ACT = (u16*)(w + (32ull << 20));     // 8 MB (ML aliases during attn)
  u16* XB  = (u16*)(w + (40ull << 20));     // 8 MB (H=ff1-out spans 40..72 during FFN)
  u16* Qb  = (u16*)(w + (48ull << 20));     // 8 MB
  u16* VT  = (u16*)(w + (56ull << 20));     // 8 MB
  u16* G   = (u16*)(w + (64ull << 20));     // 24 MB (AO aliases G head after attn)
  float* Fa = (float*)(w + (88ull << 20));  // 16 MB (OP splits 0-1 alias during attn)
  float* Fb = (float*)(w + (104ull << 20)); // 16 MB residual (OP splits 2-3 during SELF attn)
  u16* H   = XB;                            // ff1 out 32MB (XB..G head, dead in FFN)
  u16* AO  = G;                             // attn out aliases G head
  u16* OPb = (u16*)Fa;
  float2* ML = (float2*)ACT;
  float* OUT = (float*)d_out;

  dim3 wblk(32, 8);
  const int n4act = NBS * ND / 4;

  // ---- prep: input converts + ALL weight transposes (one kernel) ----
  conv_bf16<<<n4act / 256, 256, 0, stream>>>(y, ACT, n4act);
  conv_bf16<<<n4act / 256, 256, 0, stream>>>(x, XB, n4act);
  WAll wa;
  wa.s[0] = {qkv_w, Wqkv, 3 * ND, 0};
  wa.s[1] = {sa_fc_w, Wsa, ND, 3072};
  wa.s[2] = {kv_w, Wkv, 2 * ND, 4096};
  wa.s[3] = {q_w, Wq, ND, 6144};
  wa.s[4] = {ca_fc_w, Wca, ND, 7168};
  wa.s[5] = {ff1_w, Wff1, NFF, 8192};
  wa.s[6] = {ff2_w, Wff2, ND, 12288};
  wconv_all<<<16384, wblk, 0, stream>>>(wa);

  // ---- self attention block (causal: 4-way KV split over Fa+Fb, both dead here) ----
  gemm_bt<128, 0, 0><<<dim3(3 * ND / 128, NBS / 128), 256, 0, stream>>>(
      ACT, Wqkv, qkv_b, nullptr, G, NBS, 3 * ND, ND);
  vt_kern<<<dim3(NS / 64, NB * NH), 256, 0, stream>>>(G, 3 * ND, 192, 128, VT);
  attn11<1, 4><<<dim3(256, 4), 512, 0, stream>>>(G, 3 * ND, 192, G, 3 * ND, 192, 64, VT, OPb, ML);
  attn_comb<4><<<2048, 256, 0, stream>>>(OPb, ML, AO);
  gemm_bt<64, 1, 0><<<dim3(ND / 128, NBS / 64), 256, 0, stream>>>(
      AO, Wsa, sa_fc_b, Fa, nullptr, NBS, ND, ND);
  ln_kern<<<NBS, 256, 0, stream>>>(Fa, y, g1, b1, Fb, ACT);  // y1

  // ---- cross attention block (2-way split, Fa only; Fb holds y1 residual) ----
  gemm_bt<128, 0, 0><<<dim3(2 * ND / 128, NBS / 128), 256, 0, stream>>>(
      XB, Wkv, kv_b, nullptr, G, NBS, 2 * ND, ND);
  vt_kern<<<dim3(NS / 64, NB * NH), 256, 0, stream>>>(G, 2 * ND, 128, 64, VT);
  gemm_bt<64, 0, 0><<<dim3(ND / 128, NBS / 64), 256, 0, stream>>>(
      ACT, Wq, q_b, nullptr, Qb, NBS, ND, ND);
  attn11<0, 2><<<dim3(256, 2), 512, 0, stream>>>(Qb, ND, 64, G, 2 * ND, 128, 0, VT, OPb, ML);
  attn_comb<2><<<2048, 256, 0, stream>>>(OPb, ML, AO);
  gemm_bt<64, 1, 0><<<dim3(ND / 128, NBS / 64), 256, 0, stream>>>(
      AO, Wca, ca_fc_b, Fa, nullptr, NBS, ND, ND);
  ln_kern<<<NBS, 256, 0, stream>>>(Fa, Fb, g2, b2, Fb, ACT);  // y2 (in-place resid)

  // ---- FFN ----
  gemm_bt<128, 0, 1><<<dim3(NFF / 128, NBS / 128), 256, 0, stream>>>(
      ACT, Wff1, ff1_b, nullptr, H, NBS, NFF, ND);
  gemm_bt<64, 1, 0><<<dim3(ND / 128, NBS / 64), 256, 0, stream>>>(
      H, Wff2, ff2_b, Fa, nullptr, NBS, ND, NFF);
  ln_kern<<<NBS, 256, 0, stream>>>(Fa, Fb, g3, b3, OUT, ACT);
}